// Round 11
// baseline (171.936 us; speedup 1.0000x reference)
//
#include <hip/hip_runtime.h>

#define SEQ 4096
#define DIM 1024
#define NH 16
#define HD 64
#define QKVSTR 3072

typedef __attribute__((ext_vector_type(8))) short bf16x8;
typedef __attribute__((ext_vector_type(4))) float f32x4;
typedef __attribute__((ext_vector_type(16))) float f32x16;
typedef __attribute__((ext_vector_type(4))) unsigned int uint4v;

__device__ __forceinline__ unsigned short f2bf(float f) {
  unsigned int b = __float_as_uint(f);
  b = b + 0x7fffu + ((b >> 16) & 1u);
  return (unsigned short)(b >> 16);
}

__device__ __forceinline__ unsigned int cvt_pk_bf16(float lo, float hi) {
  unsigned int r;
  asm("v_cvt_pk_bf16_f32 %0, %1, %2" : "=v"(r) : "v"(lo), "v"(hi));
  return r;
}

__device__ __forceinline__ float fast_exp2(float x) {
#if __has_builtin(__builtin_amdgcn_exp2f)
  return __builtin_amdgcn_exp2f(x);
#else
  float r; asm("v_exp_f32 %0, %1" : "=v"(r) : "v"(x)); return r;
#endif
}

typedef __attribute__((address_space(3))) unsigned int lds_uint;
typedef __attribute__((address_space(1))) const unsigned int global_uint;

__device__ __forceinline__ void gload_lds16(const void* g, void* l) {
  __builtin_amdgcn_global_load_lds((global_uint*)g, (lds_uint*)l, 16, 0, 0);
}

// ---------------- fused cast fp32 -> bf16 for all 5 tensors (1 launch) ----------------
__global__ __launch_bounds__(256) void cast_all_kernel(
    const float* __restrict__ X, const float* __restrict__ wq, const float* __restrict__ wk,
    const float* __restrict__ wv, const float* __restrict__ wo,
    unsigned short* __restrict__ Xb, unsigned short* __restrict__ Wqkv,
    unsigned short* __restrict__ Wob, float qscale) {
  int i = blockIdx.x * 256 + threadIdx.x;
  const float* src;
  unsigned short* dst;
  float sc = 1.f;
  if (i < 524288) { src = X + (size_t)i * 8; dst = Xb + (size_t)i * 8; }
  else if (i < 655360) { int j = i - 524288; src = wq + (size_t)j * 8; dst = Wqkv + (size_t)j * 8; sc = qscale; }
  else if (i < 786432) { int j = i - 655360; src = wk + (size_t)j * 8; dst = Wqkv + 1048576 + (size_t)j * 8; }
  else if (i < 917504) { int j = i - 786432; src = wv + (size_t)j * 8; dst = Wqkv + 2097152 + (size_t)j * 8; }
  else { int j = i - 917504; src = wo + (size_t)j * 8; dst = Wob + (size_t)j * 8; }
  const float4* p = (const float4*)src;
  float4 x0 = p[0], x1 = p[1];
  union { unsigned short u[8]; uint4v v; } o;
  o.u[0] = f2bf(x0.x * sc); o.u[1] = f2bf(x0.y * sc);
  o.u[2] = f2bf(x0.z * sc); o.u[3] = f2bf(x0.w * sc);
  o.u[4] = f2bf(x1.x * sc); o.u[5] = f2bf(x1.y * sc);
  o.u[6] = f2bf(x1.z * sc); o.u[7] = f2bf(x1.w * sc);
  *(uint4v*)dst = o.v;
}

// ---------------- GEMM: C[M,N] = A[M,K](bf16) @ B[N,K]^T(bf16) (+bias) ----------------
// T3-minimum 2-phase + counted vmcnt(4) + bijective XCD swizzle (R10-proven).
template<int BIASMODE, int OUT_F32>
__global__ __launch_bounds__(256) void gemm_bt_kernel(
    const unsigned short* __restrict__ A, const unsigned short* __restrict__ B,
    const float* __restrict__ b0, const float* __restrict__ b1, float qscale,
    void* __restrict__ Cout, int M, int N, int K) {
  __shared__ unsigned short As[2][128 * 32];
  __shared__ unsigned short Bs[2][128 * 32];
  int tid = threadIdx.x;
  int wave = tid >> 6, lane = tid & 63;
  int g = lane >> 4, lc = lane & 15;
  int wm = wave >> 1, wn = wave & 1;

  int gx = gridDim.x;
  int wgid = blockIdx.y * gx + blockIdx.x;
  int cpx = (gx * gridDim.y) >> 3;
  int sw = (wgid & 7) * cpx + (wgid >> 3);
  int m0 = (sw / gx) * 128, n0 = (sw % gx) * 128;

  int ch0 = wave * 64 + lane;
  int r0 = ch0 >> 2, cb0 = ch0 & 3;
  int ch1 = 256 + ch0;
  int r1 = ch1 >> 2, cb1 = ch1 & 3;
  const unsigned short* Ar0 = A + (size_t)(m0 + r0) * K + cb0 * 8;
  const unsigned short* Ar1 = A + (size_t)(m0 + r1) * K + cb1 * 8;
  const unsigned short* Br0 = B + (size_t)(n0 + r0) * K + cb0 * 8;
  const unsigned short* Br1 = B + (size_t)(n0 + r1) * K + cb1 * 8;
  unsigned short* sAlo[2] = { &As[0][(wave * 64) * 8],       &As[1][(wave * 64) * 8] };
  unsigned short* sAhi[2] = { &As[0][(256 + wave * 64) * 8], &As[1][(256 + wave * 64) * 8] };
  unsigned short* sBlo[2] = { &Bs[0][(wave * 64) * 8],       &Bs[1][(wave * 64) * 8] };
  unsigned short* sBhi[2] = { &Bs[0][(256 + wave * 64) * 8], &Bs[1][(256 + wave * 64) * 8] };

  f32x4 acc[4][4] = {};

  gload_lds16(Ar0, sAlo[0]);
  gload_lds16(Ar1, sAhi[0]);
  gload_lds16(Br0, sBlo[0]);
  gload_lds16(Br1, sBhi[0]);

  int cur = 0;
  for (int k0 = 0; k0 < K; k0 += 32) {
    {
      int kn = (k0 + 32 < K) ? (k0 + 32) : 0;
      int nb = cur ^ 1;
      gload_lds16(Ar0 + kn, sAlo[nb]);
      gload_lds16(Ar1 + kn, sAhi[nb]);
      gload_lds16(Br0 + kn, sBlo[nb]);
      gload_lds16(Br1 + kn, sBhi[nb]);
    }
    asm volatile("s_waitcnt vmcnt(4)" ::: "memory");
    __builtin_amdgcn_sched_barrier(0);
    __builtin_amdgcn_s_barrier();
    __builtin_amdgcn_sched_barrier(0);

    bf16x8 af[4], bfr[4];
    for (int mf = 0; mf < 4; ++mf)
      af[mf] = *(const bf16x8*)&As[cur][(wm * 64 + mf * 16 + lc) * 32 + g * 8];
    for (int nf = 0; nf < 4; ++nf)
      bfr[nf] = *(const bf16x8*)&Bs[cur][(wn * 64 + nf * 16 + lc) * 32 + g * 8];
    for (int mf = 0; mf < 4; ++mf)
      for (int nf = 0; nf < 4; ++nf)
        acc[mf][nf] = __builtin_amdgcn_mfma_f32_16x16x32_bf16(af[mf], bfr[nf], acc[mf][nf], 0, 0, 0);

    asm volatile("" ::: "memory");
    __builtin_amdgcn_sched_barrier(0);
    __builtin_amdgcn_s_barrier();
    cur ^= 1;
  }

  for (int nf = 0; nf < 4; ++nf) {
    int col = n0 + wn * 64 + nf * 16 + lc;
    float bias = 0.f;
    if (BIASMODE == 1) {
      int sect = col >> 10, cc = col & 1023;
      bias = (sect == 0) ? b0[cc] * qscale : ((sect == 2) ? b1[cc] : 0.f);
    } else if (BIASMODE == 2) {
      bias = b0[col];
    }
    for (int mf = 0; mf < 4; ++mf) {
      int row = m0 + wm * 64 + mf * 16 + g * 4;
      for (int r = 0; r < 4; ++r) {
        float v = acc[mf][nf][r] + bias;
        if (OUT_F32) ((float*)Cout)[(size_t)(row + r) * N + col] = v;
        else ((unsigned short*)Cout)[(size_t)(row + r) * N + col] = f2bf(v);
      }
    }
  }
}

// ---------------- V transpose: V (rows of QKV, stride 3072) -> Vt[D][S] ----------------
__global__ __launch_bounds__(256) void transpose_kernel(
    const unsigned short* __restrict__ V, unsigned short* __restrict__ Vt) {
  __shared__ unsigned short Ts[64 * 72];
  int tid = threadIdx.x;
  int s0 = blockIdx.x * 64, d0 = blockIdx.y * 64;
  for (int c = 0; c < 2; ++c) {
    int q = c * 256 + tid;
    int r = q >> 3, cb = q & 7;
    uint4v v = *(const uint4v*)&V[(size_t)(s0 + r) * QKVSTR + d0 + cb * 8];
    *(uint4v*)&Ts[r * 72 + cb * 8] = v;
  }
  __syncthreads();
  for (int c = 0; c < 2; ++c) {
    int q = c * 256 + tid;
    int d = q >> 3, sc = q & 7;
    union { unsigned short u[8]; uint4v v; } ov;
    for (int j = 0; j < 8; ++j) ov.u[j] = Ts[(sc * 8 + j) * 72 + d];
    *(uint4v*)&Vt[(size_t)(d0 + d) * SEQ + s0 + sc * 8] = ov.v;
  }
}

// ---------------- flash attention, swapped-QK 32x32, KVBLK=128 two-half scheme ----------------
// R9/R10-proven inner body run twice per barrier pair (compile-time half bases).
// Per 128-kv tile: stage both halves of t+1 (8 loads), vmcnt(8) (never 0),
// 2 raw barriers. Halves the barrier/waitcnt/loop-overhead count vs KVBLK=64.
// lsum via MFMA ones-fragment; hoisted offb[] frag addressing; XCD head swizzle.
__global__ __launch_bounds__(256) void attn_kernel(
    const unsigned short* __restrict__ QKV, const unsigned short* __restrict__ Vt,
    unsigned short* __restrict__ Aout) {
  __shared__ unsigned short Qs[128 * 64];
  __shared__ unsigned short Ks[2][2][64 * 64];   // [buf][half] 64 KB
  __shared__ unsigned short Vs[2][2][64 * 64];   // (total LDS 80 KB -> 2 blocks/CU)
  int tid = threadIdx.x;
  int w = tid >> 6, lane = tid & 63;
  int hi = lane >> 5, l31 = lane & 31;

  // XCD swizzle: 512 blocks, 8 XCDs -> XCD x owns heads 2x..2x+1 (K/V fit 4MB L2)
  int bid = blockIdx.x;
  int swz = (bid & 7) * 64 + (bid >> 3);
  int h = swz >> 5;
  int q0 = (swz & 31) * 128;

  const unsigned short* Qg = QKV + h * HD;
  const unsigned short* Kg = QKV + DIM + h * HD;
  const unsigned short* Vg = Vt + (size_t)(h * HD) * SEQ;

  // loop-invariant per-lane staging offsets (chunk = c*256 + w*64 + lane)
  int ch0 = w * 64 + lane;
  int r0s = ch0 >> 3, d0s = (ch0 & 7) ^ (r0s & 7);
  int ch1 = 256 + ch0;
  int r1s = ch1 >> 3, d1s = (ch1 & 7) ^ (r1s & 7);
  size_t koff0 = (size_t)r0s * QKVSTR + d0s * 8;
  size_t koff1 = (size_t)r1s * QKVSTR + d1s * 8;
  size_t voff0 = (size_t)r0s * SEQ + d0s * 8;
  size_t voff1 = (size_t)r1s * SEQ + d1s * 8;
  // LDS dest bases [buf][half]
  unsigned short* ldsK_lo[2][2], *ldsK_hi[2][2], *ldsV_lo[2][2], *ldsV_hi[2][2];
#pragma unroll
  for (int b = 0; b < 2; ++b)
#pragma unroll
    for (int hh = 0; hh < 2; ++hh) {
      ldsK_lo[b][hh] = &Ks[b][hh][(w * 64) * 8];
      ldsK_hi[b][hh] = &Ks[b][hh][(256 + w * 64) * 8];
      ldsV_lo[b][hh] = &Vs[b][hh][(w * 64) * 8];
      ldsV_hi[b][hh] = &Vs[b][hh][(256 + w * 64) * 8];
    }

  // stage Q [128][64], XOR-swizzled via pre-swizzled global source (4 loads)
  for (int c = 0; c < 4; ++c) {
    int chunk = c * 256 + w * 64 + lane;
    int row = chunk >> 3, pos = chunk & 7;
    int db = pos ^ (row & 7);
    gload_lds16(Qg + (size_t)(q0 + row) * QKVSTR + db * 8, Qs + (c * 256 + w * 64) * 8);
  }
  // stage 128-kv tile 0 (both halves, 8 loads) -> 12 outstanding
  {
    const unsigned short* K0 = Kg;
    const unsigned short* K1 = Kg + (size_t)64 * QKVSTR;
    const unsigned short* V0 = Vg;
    const unsigned short* V1 = Vg + 64;
    gload_lds16(K0 + koff0, ldsK_lo[0][0]);
    gload_lds16(K0 + koff1, ldsK_hi[0][0]);
    gload_lds16(K1 + koff0, ldsK_lo[0][1]);
    gload_lds16(K1 + koff1, ldsK_hi[0][1]);
    gload_lds16(V0 + voff0, ldsV_lo[0][0]);
    gload_lds16(V0 + voff1, ldsV_hi[0][0]);
    gload_lds16(V1 + voff0, ldsV_lo[0][1]);
    gload_lds16(V1 + voff1, ldsV_hi[0][1]);
  }
  asm volatile("s_waitcnt vmcnt(8)" ::: "memory");  // Q done; tile0 (8) in flight
  __builtin_amdgcn_sched_barrier(0);
  __builtin_amdgcn_s_barrier();

  // Q fragments in registers (B-operand: col q = l31, k = d)
  bf16x8 qf[4];
  {
    int qrow = w * 32 + l31;
    for (int dc = 0; dc < 4; ++dc) {
      int pos = 2 * dc + hi;
      qf[dc] = *(const bf16x8*)&Qs[qrow * 64 + (pos ^ (qrow & 7)) * 8];
    }
  }

  // hoisted frag byte offsets (f=1 row+32 keeps &7 -> +4096B immediate)
  int offb[4];
#pragma unroll
  for (int dc = 0; dc < 4; ++dc)
    offb[dc] = l31 * 128 + (((2 * dc + hi) ^ (l31 & 7)) * 16);

  // ones fragment for row-sum MFMA
  union { unsigned short us[8]; bf16x8 v; } one8;
#pragma unroll
  for (int j = 0; j < 8; ++j) one8.us[j] = 0x3F80;  // bf16 1.0

  f32x16 o0 = {}, o1 = {}, lsa = {};

  // proven 64-kv inner body (compile-time LDS bases)
  auto half_body = [&](const char* Kb, const char* Vb) {
    bf16x8 kf0[4], kf1[4];
#pragma unroll
    for (int dc = 0; dc < 4; ++dc) {
      kf0[dc] = *(const bf16x8*)(Kb + offb[dc]);
      kf1[dc] = *(const bf16x8*)(Kb + offb[dc] + 4096);
    }
    f32x16 st0 = {}, st1 = {};
    __builtin_amdgcn_s_setprio(1);
#pragma unroll
    for (int dc = 0; dc < 4; ++dc) {
      st0 = __builtin_amdgcn_mfma_f32_32x32x16_bf16(kf0[dc], qf[dc], st0, 0, 0, 0);
      st1 = __builtin_amdgcn_mfma_f32_32x32x16_bf16(kf1[dc], qf[dc], st1, 0, 0, 0);
    }
    __builtin_amdgcn_s_setprio(0);

    bf16x8 vf0[4], vf1[4];
#pragma unroll
    for (int c = 0; c < 4; ++c) {
      vf0[c] = *(const bf16x8*)(Vb + offb[c]);
      vf1[c] = *(const bf16x8*)(Vb + offb[c] + 4096);
    }

    float p0[16], p1[16];
#pragma unroll
    for (int r = 0; r < 16; ++r) p0[r] = fast_exp2(st0[r]);
#pragma unroll
    for (int r = 0; r < 16; ++r) p1[r] = fast_exp2(st1[r]);

    bf16x8 pa[4];
#pragma unroll
    for (int f = 0; f < 2; ++f) {
      const float* pp = f ? p1 : p0;
#pragma unroll
      for (int cc = 0; cc < 2; ++cc) {
        unsigned uLO0 = cvt_pk_bf16(pp[8 * cc + 0], pp[8 * cc + 1]);
        unsigned uLO1 = cvt_pk_bf16(pp[8 * cc + 2], pp[8 * cc + 3]);
        unsigned uHI0 = cvt_pk_bf16(pp[8 * cc + 4], pp[8 * cc + 5]);
        unsigned uHI1 = cvt_pk_bf16(pp[8 * cc + 6], pp[8 * cc + 7]);
        auto s0 = __builtin_amdgcn_permlane32_swap(uLO0, uHI0, false, false);
        auto s1 = __builtin_amdgcn_permlane32_swap(uLO1, uHI1, false, false);
        union { unsigned u[4]; bf16x8 v; } pw;
        pw.u[0] = s0[0]; pw.u[1] = s1[0]; pw.u[2] = s0[1]; pw.u[3] = s1[1];
        pa[f * 2 + cc] = pw.v;
      }
    }

    __builtin_amdgcn_s_setprio(1);
#pragma unroll
    for (int c = 0; c < 4; ++c) {
      o0 = __builtin_amdgcn_mfma_f32_32x32x16_bf16(pa[c], vf0[c], o0, 0, 0, 0);
      o1 = __builtin_amdgcn_mfma_f32_32x32x16_bf16(pa[c], vf1[c], o1, 0, 0, 0);
      lsa = __builtin_amdgcn_mfma_f32_32x32x16_bf16(pa[c], one8.v, lsa, 0, 0, 0);
    }
    __builtin_amdgcn_s_setprio(0);
  };

  int cur = 0;
  for (int t = 0; t < SEQ / 128; ++t) {
    // prefetch 128-kv tile t+1 (wraps to 0 on last iter; vmcnt invariant)
    {
      int kvn = ((t + 1) & (SEQ / 128 - 1)) * 128;
      const unsigned short* K0 = Kg + (size_t)kvn * QKVSTR;
      const unsigned short* K1 = K0 + (size_t)64 * QKVSTR;
      const unsigned short* V0 = Vg + kvn;
      const unsigned short* V1 = V0 + 64;
      int nb = cur ^ 1;
      gload_lds16(K0 + koff0, ldsK_lo[nb][0]);
      gload_lds16(K0 + koff1, ldsK_hi[nb][0]);
      gload_lds16(K1 + koff0, ldsK_lo[nb][1]);
      gload_lds16(K1 + koff1, ldsK_hi[nb][1]);
      gload_lds16(V0 + voff0, ldsV_lo[nb][0]);
      gload_lds16(V0 + voff1, ldsV_hi[nb][0]);
      gload_lds16(V1 + voff0, ldsV_lo[nb][1]);
      gload_lds16(V1 + voff1, ldsV_hi[nb][1]);
    }
    asm volatile("s_waitcnt vmcnt(8)" ::: "memory");  // tile t resident (ours)
    __builtin_amdgcn_sched_barrier(0);
    __builtin_amdgcn_s_barrier();                     // tile t resident (all waves)
    __builtin_amdgcn_sched_barrier(0);

    if (cur == 0) {
      half_body((const char*)&Ks[0][0][0], (const char*)&Vs[0][0][0]);
      half_body((const char*)&Ks[0][1][0], (const char*)&Vs[0][1][0]);
    } else {
      half_body((const char*)&Ks[1][0][0], (const char*)&Vs[1][0][0]);
      half_body((const char*)&Ks[1][1][0], (const char*)&Vs[1][1][0]);
    }

    asm volatile("" ::: "memory");
    __builtin_amdgcn_sched_barrier(0);
    __builtin_amdgcn_s_barrier();   // all reads of tile t done -> next stage may overwrite
    cur ^= 1;
  }

  // extract row-sums from lsa C-frag via 32-float LDS slice (Qs dead)
  float* Qf = (float*)Qs;
  if (l31 == 0) {
#pragma unroll
    for (int r = 0; r < 16; ++r)
      Qf[w * 32 + ((r & 3) + 8 * (r >> 2) + 4 * hi)] = lsa[r];
  }
  float inv = 1.f / Qf[w * 32 + l31];  // valid for q = l31 (both halves)
#pragma unroll
  for (int r = 0; r < 16; ++r) {
    int qr = (r & 3) + 8 * (r >> 2) + 4 * hi;
    float ir = __shfl(inv, qr + (lane & 32));
    size_t row = q0 + w * 32 + qr;
    Aout[row * DIM + h * HD + l31]      = f2bf(o0[r] * ir);
    Aout[row * DIM + h * HD + 32 + l31] = f2bf(o1[r] * ir);
  }
}

extern "C" void kernel_launch(void* const* d_in, const int* in_sizes, int n_in,
                              void* d_out, int out_size, void* d_ws, size_t ws_size,
                              hipStream_t stream) {
  (void)in_sizes; (void)n_in; (void)out_size; (void)ws_size;
  const float* X  = (const float*)d_in[0];
  const float* wq = (const float*)d_in[1];
  const float* bq = (const float*)d_in[2];
  const float* wk = (const float*)d_in[3];
  const float* wv = (const float*)d_in[4];
  const float* bv = (const float*)d_in[5];
  const float* wo = (const float*)d_in[6];
  const float* bo = (const float*)d_in[7];

  char* ws = (char*)d_ws;
  const size_t SZ_XD  = (size_t)SEQ * DIM * 2;      // 8 MB
  const size_t SZ_W   = (size_t)DIM * DIM * 2;      // 2 MB
  const size_t SZ_QKV = (size_t)SEQ * QKVSTR * 2;   // 24 MB
  unsigned short* Xb   = (unsigned short*)(ws);                    // reused as Ab
  unsigned short* Wqkv = (unsigned short*)(ws + SZ_XD);            // [3072][1024]
  unsigned short* Wob  = (unsigned short*)(ws + SZ_XD + 3 * SZ_W);
  unsigned short* QKVb = (unsigned short*)(ws + SZ_XD + 4 * SZ_W); // [4096][3072]
  unsigned short* Vtb  = (unsigned short*)(ws + SZ_XD + 4 * SZ_W + SZ_QKV);
  unsigned short* Ab   = Xb;

  const float QSCALE = 0.125f * 1.44269504088896f;  // fold 1/sqrt(hd) * log2(e) into Wq/bq

  // one fused cast launch: 1048576 groups of 8 -> 4096 blocks
  cast_all_kernel<<<4096, 256, 0, stream>>>(X, wq, wk, wv, wo, Xb, Wqkv, Wob, QSCALE);

  // fused QKV projection: [4096][3072] bf16
  gemm_bt_kernel<1, 0><<<dim3(QKVSTR / 128, SEQ / 128), 256, 0, stream>>>(
      Xb, Wqkv, bq, bv, QSCALE, QKVb, SEQ, QKVSTR, DIM);

  // V^T: [1024][4096]
  transpose_kernel<<<dim3(SEQ / 64, DIM / 64), 256, 0, stream>>>(QKVb + 2 * DIM, Vtb);

  attn_kernel<<<SEQ / 128 * NH, 256, 0, stream>>>(QKVb, Vtb, Ab);

  // output projection (f32 out)
  gemm_bt_kernel<2, 1><<<dim3(DIM / 128, SEQ / 128), 256, 0, stream>>>(
      Ab, Wob, bo, nullptr, 1.f, d_out, SEQ, DIM, DIM);
}

// Round 12
// 167.273 us; speedup vs baseline: 1.0279x; 1.0279x over previous
//
#include <hip/hip_runtime.h>

#define SEQ 4096
#define DIM 1024
#define NH 16
#define HD 64
#define QKVSTR 3072

typedef __attribute__((ext_vector_type(8))) short bf16x8;
typedef __attribute__((ext_vector_type(4))) float f32x4;
typedef __attribute__((ext_vector_type(16))) float f32x16;
typedef __attribute__((ext_vector_type(4))) unsigned int uint4v;

__device__ __forceinline__ unsigned short f2bf(float f) {
  unsigned int b = __float_as_uint(f);
  b = b + 0x7fffu + ((b >> 16) & 1u);
  return (unsigned short)(b >> 16);
}

__device__ __forceinline__ unsigned int cvt_pk_bf16(float lo, float hi) {
  unsigned int r;
  asm("v_cvt_pk_bf16_f32 %0, %1, %2" : "=v"(r) : "v"(lo), "v"(hi));
  return r;
}

__device__ __forceinline__ float fast_exp2(float x) {
#if __has_builtin(__builtin_amdgcn_exp2f)
  return __builtin_amdgcn_exp2f(x);
#else
  float r; asm("v_exp_f32 %0, %1" : "=v"(r) : "v"(x)); return r;
#endif
}

typedef __attribute__((address_space(3))) unsigned int lds_uint;
typedef __attribute__((address_space(1))) const unsigned int global_uint;

__device__ __forceinline__ void gload_lds16(const void* g, void* l) {
  __builtin_amdgcn_global_load_lds((global_uint*)g, (lds_uint*)l, 16, 0, 0);
}

// ---------------- fused cast fp32 -> bf16 for all 5 tensors (1 launch) ----------------
__global__ __launch_bounds__(256) void cast_all_kernel(
    const float* __restrict__ X, const float* __restrict__ wq, const float* __restrict__ wk,
    const float* __restrict__ wv, const float* __restrict__ wo,
    unsigned short* __restrict__ Xb, unsigned short* __restrict__ Wqkv,
    unsigned short* __restrict__ Wob, float qscale) {
  int i = blockIdx.x * 256 + threadIdx.x;
  const float* src;
  unsigned short* dst;
  float sc = 1.f;
  if (i < 524288) { src = X + (size_t)i * 8; dst = Xb + (size_t)i * 8; }
  else if (i < 655360) { int j = i - 524288; src = wq + (size_t)j * 8; dst = Wqkv + (size_t)j * 8; sc = qscale; }
  else if (i < 786432) { int j = i - 655360; src = wk + (size_t)j * 8; dst = Wqkv + 1048576 + (size_t)j * 8; }
  else if (i < 917504) { int j = i - 786432; src = wv + (size_t)j * 8; dst = Wqkv + 2097152 + (size_t)j * 8; }
  else { int j = i - 917504; src = wo + (size_t)j * 8; dst = Wob + (size_t)j * 8; }
  const float4* p = (const float4*)src;
  float4 x0 = p[0], x1 = p[1];
  union { unsigned short u[8]; uint4v v; } o;
  o.u[0] = f2bf(x0.x * sc); o.u[1] = f2bf(x0.y * sc);
  o.u[2] = f2bf(x0.z * sc); o.u[3] = f2bf(x0.w * sc);
  o.u[4] = f2bf(x1.x * sc); o.u[5] = f2bf(x1.y * sc);
  o.u[6] = f2bf(x1.z * sc); o.u[7] = f2bf(x1.w * sc);
  *(uint4v*)dst = o.v;
}

// ---------------- GEMM: C[M,N] = A[M,K](bf16) @ B[N,K]^T(bf16) (+bias) ----------------
// T3-minimum 2-phase + counted vmcnt(4) + bijective XCD swizzle (R10-proven).
// BIASMODE==1 additionally writes the V section (col>=2048) TRANSPOSED into Vt
// (fuses the old transpose kernel into the epilogue; same scalar store count).
template<int BIASMODE, int OUT_F32>
__global__ __launch_bounds__(256) void gemm_bt_kernel(
    const unsigned short* __restrict__ A, const unsigned short* __restrict__ B,
    const float* __restrict__ b0, const float* __restrict__ b1, float qscale,
    void* __restrict__ Cout, unsigned short* __restrict__ Vt, int M, int N, int K) {
  __shared__ unsigned short As[2][128 * 32];
  __shared__ unsigned short Bs[2][128 * 32];
  int tid = threadIdx.x;
  int wave = tid >> 6, lane = tid & 63;
  int g = lane >> 4, lc = lane & 15;
  int wm = wave >> 1, wn = wave & 1;

  int gx = gridDim.x;
  int wgid = blockIdx.y * gx + blockIdx.x;
  int cpx = (gx * gridDim.y) >> 3;
  int sw = (wgid & 7) * cpx + (wgid >> 3);
  int m0 = (sw / gx) * 128, n0 = (sw % gx) * 128;

  int ch0 = wave * 64 + lane;
  int r0 = ch0 >> 2, cb0 = ch0 & 3;
  int ch1 = 256 + ch0;
  int r1 = ch1 >> 2, cb1 = ch1 & 3;
  const unsigned short* Ar0 = A + (size_t)(m0 + r0) * K + cb0 * 8;
  const unsigned short* Ar1 = A + (size_t)(m0 + r1) * K + cb1 * 8;
  const unsigned short* Br0 = B + (size_t)(n0 + r0) * K + cb0 * 8;
  const unsigned short* Br1 = B + (size_t)(n0 + r1) * K + cb1 * 8;
  unsigned short* sAlo[2] = { &As[0][(wave * 64) * 8],       &As[1][(wave * 64) * 8] };
  unsigned short* sAhi[2] = { &As[0][(256 + wave * 64) * 8], &As[1][(256 + wave * 64) * 8] };
  unsigned short* sBlo[2] = { &Bs[0][(wave * 64) * 8],       &Bs[1][(wave * 64) * 8] };
  unsigned short* sBhi[2] = { &Bs[0][(256 + wave * 64) * 8], &Bs[1][(256 + wave * 64) * 8] };

  f32x4 acc[4][4] = {};

  gload_lds16(Ar0, sAlo[0]);
  gload_lds16(Ar1, sAhi[0]);
  gload_lds16(Br0, sBlo[0]);
  gload_lds16(Br1, sBhi[0]);

  int cur = 0;
  for (int k0 = 0; k0 < K; k0 += 32) {
    {
      int kn = (k0 + 32 < K) ? (k0 + 32) : 0;
      int nb = cur ^ 1;
      gload_lds16(Ar0 + kn, sAlo[nb]);
      gload_lds16(Ar1 + kn, sAhi[nb]);
      gload_lds16(Br0 + kn, sBlo[nb]);
      gload_lds16(Br1 + kn, sBhi[nb]);
    }
    asm volatile("s_waitcnt vmcnt(4)" ::: "memory");
    __builtin_amdgcn_sched_barrier(0);
    __builtin_amdgcn_s_barrier();
    __builtin_amdgcn_sched_barrier(0);

    bf16x8 af[4], bfr[4];
    for (int mf = 0; mf < 4; ++mf)
      af[mf] = *(const bf16x8*)&As[cur][(wm * 64 + mf * 16 + lc) * 32 + g * 8];
    for (int nf = 0; nf < 4; ++nf)
      bfr[nf] = *(const bf16x8*)&Bs[cur][(wn * 64 + nf * 16 + lc) * 32 + g * 8];
    for (int mf = 0; mf < 4; ++mf)
      for (int nf = 0; nf < 4; ++nf)
        acc[mf][nf] = __builtin_amdgcn_mfma_f32_16x16x32_bf16(af[mf], bfr[nf], acc[mf][nf], 0, 0, 0);

    asm volatile("" ::: "memory");
    __builtin_amdgcn_sched_barrier(0);
    __builtin_amdgcn_s_barrier();
    cur ^= 1;
  }

  for (int nf = 0; nf < 4; ++nf) {
    int col = n0 + wn * 64 + nf * 16 + lc;
    float bias = 0.f;
    if (BIASMODE == 1) {
      int sect = col >> 10, cc = col & 1023;
      bias = (sect == 0) ? b0[cc] * qscale : ((sect == 2) ? b1[cc] : 0.f);
    } else if (BIASMODE == 2) {
      bias = b0[col];
    }
    for (int mf = 0; mf < 4; ++mf) {
      int row = m0 + wm * 64 + mf * 16 + g * 4;
      for (int r = 0; r < 4; ++r) {
        float v = acc[mf][nf][r] + bias;
        if (OUT_F32) {
          ((float*)Cout)[(size_t)(row + r) * N + col] = v;
        } else if (BIASMODE == 1 && col >= 2048) {
          // fused V transpose: Vt[d][s], d = col-2048, s = row+r
          Vt[(size_t)(col - 2048) * SEQ + row + r] = f2bf(v);
        } else {
          ((unsigned short*)Cout)[(size_t)(row + r) * N + col] = f2bf(v);
        }
      }
    }
  }
}

// ---------------- flash attention, swapped-QK 32x32, counted-vmcnt pipeline ----------------
// R10-proven body, byte-identical: 2 bufs, 2 barriers/tile, vmcnt(4) never 0,
// lsum via MFMA ones-fragment, hoisted offb[] frag addressing.
__global__ __launch_bounds__(256) void attn_kernel(
    const unsigned short* __restrict__ QKV, const unsigned short* __restrict__ Vt,
    unsigned short* __restrict__ Aout) {
  __shared__ unsigned short Qs[128 * 64];
  __shared__ unsigned short Ks[2][64 * 64];
  __shared__ unsigned short Vs[2][64 * 64];
  int tid = threadIdx.x;
  int w = tid >> 6, lane = tid & 63;
  int hi = lane >> 5, l31 = lane & 31;

  // XCD swizzle: 512 blocks, 8 XCDs -> XCD x owns heads 2x..2x+1 (K/V fit 4MB L2)
  int bid = blockIdx.x;
  int swz = (bid & 7) * 64 + (bid >> 3);
  int h = swz >> 5;
  int q0 = (swz & 31) * 128;

  const unsigned short* Qg = QKV + h * HD;
  const unsigned short* Kg = QKV + DIM + h * HD;
  const unsigned short* Vg = Vt + (size_t)(h * HD) * SEQ;

  // loop-invariant per-lane staging offsets (chunk = c*256 + w*64 + lane)
  int ch0 = w * 64 + lane;
  int r0s = ch0 >> 3, d0s = (ch0 & 7) ^ (r0s & 7);
  int ch1 = 256 + ch0;
  int r1s = ch1 >> 3, d1s = (ch1 & 7) ^ (r1s & 7);
  size_t koff0 = (size_t)r0s * QKVSTR + d0s * 8;
  size_t koff1 = (size_t)r1s * QKVSTR + d1s * 8;
  size_t voff0 = (size_t)r0s * SEQ + d0s * 8;
  size_t voff1 = (size_t)r1s * SEQ + d1s * 8;
  unsigned short* ldsK_lo[2] = { &Ks[0][(w * 64) * 8],       &Ks[1][(w * 64) * 8] };
  unsigned short* ldsK_hi[2] = { &Ks[0][(256 + w * 64) * 8], &Ks[1][(256 + w * 64) * 8] };
  unsigned short* ldsV_lo[2] = { &Vs[0][(w * 64) * 8],       &Vs[1][(w * 64) * 8] };
  unsigned short* ldsV_hi[2] = { &Vs[0][(256 + w * 64) * 8], &Vs[1][(256 + w * 64) * 8] };

  // stage Q [128][64], XOR-swizzled via pre-swizzled global source (4 loads)
  for (int c = 0; c < 4; ++c) {
    int chunk = c * 256 + w * 64 + lane;
    int row = chunk >> 3, pos = chunk & 7;
    int db = pos ^ (row & 7);
    gload_lds16(Qg + (size_t)(q0 + row) * QKVSTR + db * 8, Qs + (c * 256 + w * 64) * 8);
  }
  // stage K/V tile 0 (4 loads) -> 8 outstanding
  gload_lds16(Kg + koff0, ldsK_lo[0]);
  gload_lds16(Kg + koff1, ldsK_hi[0]);
  gload_lds16(Vg + voff0, ldsV_lo[0]);
  gload_lds16(Vg + voff1, ldsV_hi[0]);
  asm volatile("s_waitcnt vmcnt(4)" ::: "memory");  // Q done; tile0 in flight
  __builtin_amdgcn_sched_barrier(0);
  __builtin_amdgcn_s_barrier();

  // Q fragments in registers (B-operand: col q = l31, k = d)
  bf16x8 qf[4];
  {
    int qrow = w * 32 + l31;
    for (int dc = 0; dc < 4; ++dc) {
      int pos = 2 * dc + hi;
      qf[dc] = *(const bf16x8*)&Qs[qrow * 64 + (pos ^ (qrow & 7)) * 8];
    }
  }

  // hoisted frag byte offsets (f=1 row+32 keeps &7 -> +4096B immediate)
  int offb[4];
#pragma unroll
  for (int dc = 0; dc < 4; ++dc)
    offb[dc] = l31 * 128 + (((2 * dc + hi) ^ (l31 & 7)) * 16);
  const char* KbA = (const char*)&Ks[0][0];
  const char* KbB = (const char*)&Ks[1][0];
  const char* VbA = (const char*)&Vs[0][0];
  const char* VbB = (const char*)&Vs[1][0];

  // ones fragment for row-sum MFMA
  union { unsigned short us[8]; bf16x8 v; } one8;
#pragma unroll
  for (int j = 0; j < 8; ++j) one8.us[j] = 0x3F80;  // bf16 1.0

  f32x16 o0 = {}, o1 = {}, lsa = {};
  int cur = 0;

  for (int t = 0; t < SEQ / 64; ++t) {
    // prefetch tile t+1 (wraps to 0 on last iter to keep vmcnt invariant)
    {
      int kvn = ((t + 1) & (SEQ / 64 - 1)) * 64;
      const unsigned short* Kt = Kg + (size_t)kvn * QKVSTR;
      const unsigned short* Vtt = Vg + kvn;
      int nb = cur ^ 1;
      gload_lds16(Kt + koff0, ldsK_lo[nb]);
      gload_lds16(Kt + koff1, ldsK_hi[nb]);
      gload_lds16(Vtt + voff0, ldsV_lo[nb]);
      gload_lds16(Vtt + voff1, ldsV_hi[nb]);
    }
    asm volatile("s_waitcnt vmcnt(4)" ::: "memory");  // tile t resident (ours)
    __builtin_amdgcn_sched_barrier(0);
    __builtin_amdgcn_s_barrier();                     // tile t resident (all waves)
    __builtin_amdgcn_sched_barrier(0);

    const char* Kb = cur ? KbB : KbA;
    const char* Vb = cur ? VbB : VbA;

    // K fragments (A-operand: row kv = f*32+l31, k = d)
    bf16x8 kf0[4], kf1[4];
#pragma unroll
    for (int dc = 0; dc < 4; ++dc) {
      kf0[dc] = *(const bf16x8*)(Kb + offb[dc]);
      kf1[dc] = *(const bf16x8*)(Kb + offb[dc] + 4096);
    }
    f32x16 st0 = {}, st1 = {};
    __builtin_amdgcn_s_setprio(1);
#pragma unroll
    for (int dc = 0; dc < 4; ++dc) {
      st0 = __builtin_amdgcn_mfma_f32_32x32x16_bf16(kf0[dc], qf[dc], st0, 0, 0, 0);
      st1 = __builtin_amdgcn_mfma_f32_32x32x16_bf16(kf1[dc], qf[dc], st1, 0, 0, 0);
    }
    __builtin_amdgcn_s_setprio(0);

    // V fragments early (latency hides under exp/pack)
    bf16x8 vf0[4], vf1[4];
#pragma unroll
    for (int c = 0; c < 4; ++c) {
      vf0[c] = *(const bf16x8*)(Vb + offb[c]);
      vf1[c] = *(const bf16x8*)(Vb + offb[c] + 4096);
    }

    // P = exp2(S^T) in-register (row-sum handled by MFMA)
    float p0[16], p1[16];
#pragma unroll
    for (int r = 0; r < 16; ++r) p0[r] = fast_exp2(st0[r]);
#pragma unroll
    for (int r = 0; r < 16; ++r) p1[r] = fast_exp2(st1[r]);

    // pack to bf16 + permlane32_swap -> PV A-frags pa[c] (T12)
    bf16x8 pa[4];
#pragma unroll
    for (int f = 0; f < 2; ++f) {
      const float* pp = f ? p1 : p0;
#pragma unroll
      for (int cc = 0; cc < 2; ++cc) {
        unsigned uLO0 = cvt_pk_bf16(pp[8 * cc + 0], pp[8 * cc + 1]);
        unsigned uLO1 = cvt_pk_bf16(pp[8 * cc + 2], pp[8 * cc + 3]);
        unsigned uHI0 = cvt_pk_bf16(pp[8 * cc + 4], pp[8 * cc + 5]);
        unsigned uHI1 = cvt_pk_bf16(pp[8 * cc + 6], pp[8 * cc + 7]);
        auto s0 = __builtin_amdgcn_permlane32_swap(uLO0, uHI0, false, false);
        auto s1 = __builtin_amdgcn_permlane32_swap(uLO1, uHI1, false, false);
        union { unsigned u[4]; bf16x8 v; } pw;
        pw.u[0] = s0[0]; pw.u[1] = s1[0]; pw.u[2] = s0[1]; pw.u[3] = s1[1];
        pa[f * 2 + cc] = pw.v;
      }
    }

    // PV + row-sum (lsa = P @ ones)
    __builtin_amdgcn_s_setprio(1);
#pragma unroll
    for (int c = 0; c < 4; ++c) {
      o0 = __builtin_amdgcn_mfma_f32_32x32x16_bf16(pa[c], vf0[c], o0, 0, 0, 0);
      o1 = __builtin_amdgcn_mfma_f32_32x32x16_bf16(pa[c], vf1[c], o1, 0, 0, 0);
      lsa = __builtin_amdgcn_mfma_f32_32x32x16_bf16(pa[c], one8.v, lsa, 0, 0, 0);
    }
    __builtin_amdgcn_s_setprio(0);

    asm volatile("" ::: "memory");
    __builtin_amdgcn_sched_barrier(0);
    __builtin_amdgcn_s_barrier();   // all reads of tile t done -> next stage may overwrite
    cur ^= 1;
  }

  // extract row-sums from lsa C-frag via 32-float LDS slice (Qs dead)
  float* Qf = (float*)Qs;
  if (l31 == 0) {
#pragma unroll
    for (int r = 0; r < 16; ++r)
      Qf[w * 32 + ((r & 3) + 8 * (r >> 2) + 4 * hi)] = lsa[r];
  }
  float inv = 1.f / Qf[w * 32 + l31];  // valid for q = l31 (both halves)
#pragma unroll
  for (int r = 0; r < 16; ++r) {
    int qr = (r & 3) + 8 * (r >> 2) + 4 * hi;
    float ir = __shfl(inv, qr + (lane & 32));
    size_t row = q0 + w * 32 + qr;
    Aout[row * DIM + h * HD + l31]      = f2bf(o0[r] * ir);
    Aout[row * DIM + h * HD + 32 + l31] = f2bf(o1[r] * ir);
  }
}

extern "C" void kernel_launch(void* const* d_in, const int* in_sizes, int n_in,
                              void* d_out, int out_size, void* d_ws, size_t ws_size,
                              hipStream_t stream) {
  (void)in_sizes; (void)n_in; (void)out_size; (void)ws_size;
  const float* X  = (const float*)d_in[0];
  const float* wq = (const float*)d_in[1];
  const float* bq = (const float*)d_in[2];
  const float* wk = (const float*)d_in[3];
  const float* wv = (const float*)d_in[4];
  const float* bv = (const float*)d_in[5];
  const float* wo = (const float*)d_in[6];
  const float* bo = (const float*)d_in[7];

  char* ws = (char*)d_ws;
  const size_t SZ_XD  = (size_t)SEQ * DIM * 2;      // 8 MB
  const size_t SZ_W   = (size_t)DIM * DIM * 2;      // 2 MB
  const size_t SZ_QKV = (size_t)SEQ * QKVSTR * 2;   // 24 MB
  unsigned short* Xb   = (unsigned short*)(ws);                    // reused as Ab
  unsigned short* Wqkv = (unsigned short*)(ws + SZ_XD);            // [3072][1024]
  unsigned short* Wob  = (unsigned short*)(ws + SZ_XD + 3 * SZ_W);
  unsigned short* QKVb = (unsigned short*)(ws + SZ_XD + 4 * SZ_W); // [4096][3072]
  unsigned short* Vtb  = (unsigned short*)(ws + SZ_XD + 4 * SZ_W + SZ_QKV);
  unsigned short* Ab   = Xb;

  const float QSCALE = 0.125f * 1.44269504088896f;  // fold 1/sqrt(hd) * log2(e) into Wq/bq

  // one fused cast launch: 1048576 groups of 8 -> 4096 blocks
  cast_all_kernel<<<4096, 256, 0, stream>>>(X, wq, wk, wv, wo, Xb, Wqkv, Wob, QSCALE);

  // fused QKV projection: [4096][3072] bf16; V section written transposed to Vtb
  gemm_bt_kernel<1, 0><<<dim3(QKVSTR / 128, SEQ / 128), 256, 0, stream>>>(
      Xb, Wqkv, bq, bv, QSCALE, QKVb, Vtb, SEQ, QKVSTR, DIM);

  attn_kernel<<<SEQ / 128 * NH, 256, 0, stream>>>(QKVb, Vtb, Ab);

  // output projection (f32 out)
  gemm_bt_kernel<2, 1><<<dim3(DIM / 128, SEQ / 128), 256, 0, stream>>>(
      Ab, Wob, bo, nullptr, 1.f, d_out, nullptr, SEQ, DIM, DIM);
}

// Round 13
// 165.673 us; speedup vs baseline: 1.0378x; 1.0097x over previous
//
#include <hip/hip_runtime.h>

#define SEQ 4096
#define DIM 1024
#define NH 16
#define HD 64
#define QKVSTR 3072

typedef __attribute__((ext_vector_type(8))) short bf16x8;
typedef __attribute__((ext_vector_type(4))) float f32x4;
typedef __attribute__((ext_vector_type(16))) float f32x16;
typedef __attribute__((ext_vector_type(4))) unsigned int uint4v;

__device__ __forceinline__ unsigned short f2bf(float f) {
  unsigned int b = __float_as_uint(f);
  b = b + 0x7fffu + ((b >> 16) & 1u);
  return (unsigned short)(b >> 16);
}

__device__ __forceinline__ unsigned int cvt_pk_bf16(float lo, float hi) {
  unsigned int r;
  asm("v_cvt_pk_bf16_f32 %0, %1, %2" : "=v"(r) : "v"(lo), "v"(hi));
  return r;
}

__device__ __forceinline__ float fast_exp2(float x) {
#if __has_builtin(__builtin_amdgcn_exp2f)
  return __builtin_amdgcn_exp2f(x);
#else
  float r; asm("v_exp_f32 %0, %1" : "=v"(r) : "v"(x)); return r;
#endif
}

typedef __attribute__((address_space(3))) unsigned int lds_uint;
typedef __attribute__((address_space(1))) const unsigned int global_uint;

__device__ __forceinline__ void gload_lds16(const void* g, void* l) {
  __builtin_amdgcn_global_load_lds((global_uint*)g, (lds_uint*)l, 16, 0, 0);
}

// ---------------- fused cast fp32 -> bf16 for all 5 tensors (1 launch) ----------------
__global__ __launch_bounds__(256) void cast_all_kernel(
    const float* __restrict__ X, const float* __restrict__ wq, const float* __restrict__ wk,
    const float* __restrict__ wv, const float* __restrict__ wo,
    unsigned short* __restrict__ Xb, unsigned short* __restrict__ Wqkv,
    unsigned short* __restrict__ Wob, float qscale) {
  int i = blockIdx.x * 256 + threadIdx.x;
  const float* src;
  unsigned short* dst;
  float sc = 1.f;
  if (i < 524288) { src = X + (size_t)i * 8; dst = Xb + (size_t)i * 8; }
  else if (i < 655360) { int j = i - 524288; src = wq + (size_t)j * 8; dst = Wqkv + (size_t)j * 8; sc = qscale; }
  else if (i < 786432) { int j = i - 655360; src = wk + (size_t)j * 8; dst = Wqkv + 1048576 + (size_t)j * 8; }
  else if (i < 917504) { int j = i - 786432; src = wv + (size_t)j * 8; dst = Wqkv + 2097152 + (size_t)j * 8; }
  else { int j = i - 917504; src = wo + (size_t)j * 8; dst = Wob + (size_t)j * 8; }
  const float4* p = (const float4*)src;
  float4 x0 = p[0], x1 = p[1];
  union { unsigned short u[8]; uint4v v; } o;
  o.u[0] = f2bf(x0.x * sc); o.u[1] = f2bf(x0.y * sc);
  o.u[2] = f2bf(x0.z * sc); o.u[3] = f2bf(x0.w * sc);
  o.u[4] = f2bf(x1.x * sc); o.u[5] = f2bf(x1.y * sc);
  o.u[6] = f2bf(x1.z * sc); o.u[7] = f2bf(x1.w * sc);
  *(uint4v*)dst = o.v;
}

// ---------------- GEMM: C[M,N] = A[M,K](bf16) @ B[N,K]^T(bf16) (+bias) ----------------
// T3-minimum 2-phase + counted vmcnt(4) + bijective XCD swizzle (R10-proven).
// BIASMODE==1 additionally writes the V section (col>=2048) TRANSPOSED into Vt.
template<int BIASMODE, int OUT_F32>
__global__ __launch_bounds__(256) void gemm_bt_kernel(
    const unsigned short* __restrict__ A, const unsigned short* __restrict__ B,
    const float* __restrict__ b0, const float* __restrict__ b1, float qscale,
    void* __restrict__ Cout, unsigned short* __restrict__ Vt, int M, int N, int K) {
  __shared__ unsigned short As[2][128 * 32];
  __shared__ unsigned short Bs[2][128 * 32];
  int tid = threadIdx.x;
  int wave = tid >> 6, lane = tid & 63;
  int g = lane >> 4, lc = lane & 15;
  int wm = wave >> 1, wn = wave & 1;

  int gx = gridDim.x;
  int wgid = blockIdx.y * gx + blockIdx.x;
  int cpx = (gx * gridDim.y) >> 3;
  int sw = (wgid & 7) * cpx + (wgid >> 3);
  int m0 = (sw / gx) * 128, n0 = (sw % gx) * 128;

  int ch0 = wave * 64 + lane;
  int r0 = ch0 >> 2, cb0 = ch0 & 3;
  int ch1 = 256 + ch0;
  int r1 = ch1 >> 2, cb1 = ch1 & 3;
  const unsigned short* Ar0 = A + (size_t)(m0 + r0) * K + cb0 * 8;
  const unsigned short* Ar1 = A + (size_t)(m0 + r1) * K + cb1 * 8;
  const unsigned short* Br0 = B + (size_t)(n0 + r0) * K + cb0 * 8;
  const unsigned short* Br1 = B + (size_t)(n0 + r1) * K + cb1 * 8;
  unsigned short* sAlo[2] = { &As[0][(wave * 64) * 8],       &As[1][(wave * 64) * 8] };
  unsigned short* sAhi[2] = { &As[0][(256 + wave * 64) * 8], &As[1][(256 + wave * 64) * 8] };
  unsigned short* sBlo[2] = { &Bs[0][(wave * 64) * 8],       &Bs[1][(wave * 64) * 8] };
  unsigned short* sBhi[2] = { &Bs[0][(256 + wave * 64) * 8], &Bs[1][(256 + wave * 64) * 8] };

  f32x4 acc[4][4] = {};

  gload_lds16(Ar0, sAlo[0]);
  gload_lds16(Ar1, sAhi[0]);
  gload_lds16(Br0, sBlo[0]);
  gload_lds16(Br1, sBhi[0]);

  int cur = 0;
  for (int k0 = 0; k0 < K; k0 += 32) {
    {
      int kn = (k0 + 32 < K) ? (k0 + 32) : 0;
      int nb = cur ^ 1;
      gload_lds16(Ar0 + kn, sAlo[nb]);
      gload_lds16(Ar1 + kn, sAhi[nb]);
      gload_lds16(Br0 + kn, sBlo[nb]);
      gload_lds16(Br1 + kn, sBhi[nb]);
    }
    asm volatile("s_waitcnt vmcnt(4)" ::: "memory");
    __builtin_amdgcn_sched_barrier(0);
    __builtin_amdgcn_s_barrier();
    __builtin_amdgcn_sched_barrier(0);

    bf16x8 af[4], bfr[4];
    for (int mf = 0; mf < 4; ++mf)
      af[mf] = *(const bf16x8*)&As[cur][(wm * 64 + mf * 16 + lc) * 32 + g * 8];
    for (int nf = 0; nf < 4; ++nf)
      bfr[nf] = *(const bf16x8*)&Bs[cur][(wn * 64 + nf * 16 + lc) * 32 + g * 8];
    for (int mf = 0; mf < 4; ++mf)
      for (int nf = 0; nf < 4; ++nf)
        acc[mf][nf] = __builtin_amdgcn_mfma_f32_16x16x32_bf16(af[mf], bfr[nf], acc[mf][nf], 0, 0, 0);

    asm volatile("" ::: "memory");
    __builtin_amdgcn_sched_barrier(0);
    __builtin_amdgcn_s_barrier();
    cur ^= 1;
  }

  for (int nf = 0; nf < 4; ++nf) {
    int col = n0 + wn * 64 + nf * 16 + lc;
    float bias = 0.f;
    if (BIASMODE == 1) {
      int sect = col >> 10, cc = col & 1023;
      bias = (sect == 0) ? b0[cc] * qscale : ((sect == 2) ? b1[cc] : 0.f);
    } else if (BIASMODE == 2) {
      bias = b0[col];
    }
    for (int mf = 0; mf < 4; ++mf) {
      int row = m0 + wm * 64 + mf * 16 + g * 4;
      for (int r = 0; r < 4; ++r) {
        float v = acc[mf][nf][r] + bias;
        if (OUT_F32) {
          ((float*)Cout)[(size_t)(row + r) * N + col] = v;
        } else if (BIASMODE == 1 && col >= 2048) {
          Vt[(size_t)(col - 2048) * SEQ + row + r] = f2bf(v);
        } else {
          ((unsigned short*)Cout)[(size_t)(row + r) * N + col] = f2bf(v);
        }
      }
    }
  }
}

// ---------------- flash attention: 8-wave in-block kv-split x2 (R7 body, uncapped VGPR) ----------------
// Waves 0-3 (grp 0) do kv tiles 0..31, waves 4-7 (grp 1) do 32..63 over a shared
// Q tile. No-max softmax -> halves combine by pure addition (exact, via LDS).
// Per-tile sync: R4/R6-proven template (2 bufs, 2 barriers, counted vmcnt(4)).
// R7 proved correctness; its perf failure was __launch_bounds__(512,4) forcing a
// 64-VGPR cap -> scratch spill (WRITE_SIZE 626 MB). Here: (512,1) -> natural alloc.
__global__ __launch_bounds__(512, 1) void attn_kernel(
    const unsigned short* __restrict__ QKV, const unsigned short* __restrict__ Vt,
    unsigned short* __restrict__ Aout) {
  __shared__ unsigned short Qs[128 * 64];        // 16 KB
  __shared__ unsigned short Ks[2][2][64 * 64];   // [grp][buf] 32 KB
  __shared__ unsigned short Vs[2][2][64 * 64];   // 32 KB  (total 80 KB -> 2 blocks/CU)
  int tid = threadIdx.x;
  int w = tid >> 6, lane = tid & 63;
  int hi = lane >> 5, l31 = lane & 31;
  int qw = w & 3, grp = w >> 2;

  // XCD swizzle: 512 blocks, 8 XCDs -> XCD x owns heads 2x..2x+1 (K/V fit 4MB L2)
  int bid = blockIdx.x;
  int swz = (bid & 7) * 64 + (bid >> 3);
  int h = swz >> 5;
  int q0 = (swz & 31) * 128;

  const unsigned short* Qg = QKV + h * HD;
  const unsigned short* Kg = QKV + DIM + h * HD;
  const unsigned short* Vg = Vt + (size_t)(h * HD) * SEQ;
  int kvbase = grp * (SEQ / 2);

  // staging offsets: 4 waves of each group stage the group's K/V tile
  int ch0 = qw * 64 + lane;
  int r0s = ch0 >> 3, d0s = (ch0 & 7) ^ (r0s & 7);
  int ch1 = 256 + ch0;
  int r1s = ch1 >> 3, d1s = (ch1 & 7) ^ (r1s & 7);
  size_t koff0 = (size_t)r0s * QKVSTR + d0s * 8;
  size_t koff1 = (size_t)r1s * QKVSTR + d1s * 8;
  size_t voff0 = (size_t)r0s * SEQ + d0s * 8;
  size_t voff1 = (size_t)r1s * SEQ + d1s * 8;
  unsigned short* sKlo[2] = { &Ks[grp][0][(qw * 64) * 8],       &Ks[grp][1][(qw * 64) * 8] };
  unsigned short* sKhi[2] = { &Ks[grp][0][(256 + qw * 64) * 8], &Ks[grp][1][(256 + qw * 64) * 8] };
  unsigned short* sVlo[2] = { &Vs[grp][0][(qw * 64) * 8],       &Vs[grp][1][(qw * 64) * 8] };
  unsigned short* sVhi[2] = { &Vs[grp][0][(256 + qw * 64) * 8], &Vs[grp][1][(256 + qw * 64) * 8] };

  // stage Q [128][64]: 1024 chunks by 8 waves, XOR-swizzled via global source
  for (int c = 0; c < 2; ++c) {
    int chunk = c * 512 + w * 64 + lane;
    int row = chunk >> 3, pos = chunk & 7;
    int db = pos ^ (row & 7);
    gload_lds16(Qg + (size_t)(q0 + row) * QKVSTR + db * 8, Qs + (c * 512 + w * 64) * 8);
  }
  // stage this group's K/V tile 0
  {
    const unsigned short* Kt = Kg + (size_t)kvbase * QKVSTR;
    const unsigned short* Vtt = Vg + kvbase;
    gload_lds16(Kt + koff0, sKlo[0]);
    gload_lds16(Kt + koff1, sKhi[0]);
    gload_lds16(Vtt + voff0, sVlo[0]);
    gload_lds16(Vtt + voff1, sVhi[0]);
  }
  asm volatile("s_waitcnt vmcnt(4)" ::: "memory");  // Q landed; tile0 in flight
  __builtin_amdgcn_sched_barrier(0);
  __builtin_amdgcn_s_barrier();

  // Q fragments (B-operand: col q = l31, k = d); both groups read same q-rows
  bf16x8 qf[4];
  {
    int qrow = qw * 32 + l31;
    for (int dc = 0; dc < 4; ++dc) {
      int pos = 2 * dc + hi;
      qf[dc] = *(const bf16x8*)&Qs[qrow * 64 + (pos ^ (qrow & 7)) * 8];
    }
  }

  // hoisted LDS byte offsets for kf/vf (f=1 row+32 keeps &7 -> +4096B imm)
  int offb[4];
#pragma unroll
  for (int dc = 0; dc < 4; ++dc)
    offb[dc] = l31 * 128 + (((2 * dc + hi) ^ (l31 & 7)) * 16);
  const char* KbA = (const char*)&Ks[grp][0][0];
  const char* KbB = (const char*)&Ks[grp][1][0];
  const char* VbA = (const char*)&Vs[grp][0][0];
  const char* VbB = (const char*)&Vs[grp][1][0];

  f32x16 o0 = {}, o1 = {};
  float la0 = 0.f, la1 = 0.f, la2 = 0.f, la3 = 0.f;

  auto body = [&](int t, int CUR) {
    int NB = CUR ^ 1;
    // prefetch this group's tile t+1 (wraps within half; vmcnt invariant)
    int kvn = kvbase + (((t + 1) & 31) << 6);
    const unsigned short* Kt = Kg + (size_t)kvn * QKVSTR;
    const unsigned short* Vtt = Vg + kvn;
    gload_lds16(Kt + koff0, sKlo[NB]);
    gload_lds16(Kt + koff1, sKhi[NB]);
    gload_lds16(Vtt + voff0, sVlo[NB]);
    gload_lds16(Vtt + voff1, sVhi[NB]);
    asm volatile("s_waitcnt vmcnt(4)" ::: "memory");  // tile t resident (this wave)
    __builtin_amdgcn_sched_barrier(0);
    __builtin_amdgcn_s_barrier();                     // tile t resident (all waves)
    __builtin_amdgcn_sched_barrier(0);

    const char* Kb = CUR ? KbB : KbA;
    const char* Vb = CUR ? VbB : VbA;
    bf16x8 kf0[4], kf1[4];
#pragma unroll
    for (int dc = 0; dc < 4; ++dc) {
      kf0[dc] = *(const bf16x8*)(Kb + offb[dc]);
      kf1[dc] = *(const bf16x8*)(Kb + offb[dc] + 4096);
    }
    f32x16 st0 = {}, st1 = {};
    __builtin_amdgcn_s_setprio(1);
#pragma unroll
    for (int dc = 0; dc < 4; ++dc) {
      st0 = __builtin_amdgcn_mfma_f32_32x32x16_bf16(kf0[dc], qf[dc], st0, 0, 0, 0);
      st1 = __builtin_amdgcn_mfma_f32_32x32x16_bf16(kf1[dc], qf[dc], st1, 0, 0, 0);
    }
    __builtin_amdgcn_s_setprio(0);

    // V fragments early (latency hides under exp/pack)
    bf16x8 vf0[4], vf1[4];
#pragma unroll
    for (int c = 0; c < 4; ++c) {
      vf0[c] = *(const bf16x8*)(Vb + offb[c]);
      vf1[c] = *(const bf16x8*)(Vb + offb[c] + 4096);
    }

    // P = exp2(S^T); 4 independent lsum accumulators (break dep chain)
    float p0[16], p1[16];
#pragma unroll
    for (int r = 0; r < 16; r += 4) {
      p0[r] = fast_exp2(st0[r]); p0[r + 1] = fast_exp2(st0[r + 1]);
      p0[r + 2] = fast_exp2(st0[r + 2]); p0[r + 3] = fast_exp2(st0[r + 3]);
      la0 += p0[r]; la1 += p0[r + 1]; la2 += p0[r + 2]; la3 += p0[r + 3];
    }
#pragma unroll
    for (int r = 0; r < 16; r += 4) {
      p1[r] = fast_exp2(st1[r]); p1[r + 1] = fast_exp2(st1[r + 1]);
      p1[r + 2] = fast_exp2(st1[r + 2]); p1[r + 3] = fast_exp2(st1[r + 3]);
      la0 += p1[r]; la1 += p1[r + 1]; la2 += p1[r + 2]; la3 += p1[r + 3];
    }

    // pack to bf16 + permlane32_swap -> PV A-frags pa[c] (T12)
    bf16x8 pa[4];
#pragma unroll
    for (int f = 0; f < 2; ++f) {
      const float* pp = f ? p1 : p0;
#pragma unroll
      for (int cc = 0; cc < 2; ++cc) {
        unsigned uLO0 = cvt_pk_bf16(pp[8 * cc + 0], pp[8 * cc + 1]);
        unsigned uLO1 = cvt_pk_bf16(pp[8 * cc + 2], pp[8 * cc + 3]);
        unsigned uHI0 = cvt_pk_bf16(pp[8 * cc + 4], pp[8 * cc + 5]);
        unsigned uHI1 = cvt_pk_bf16(pp[8 * cc + 6], pp[8 * cc + 7]);
        auto s0 = __builtin_amdgcn_permlane32_swap(uLO0, uHI0, false, false);
        auto s1 = __builtin_amdgcn_permlane32_swap(uLO1, uHI1, false, false);
        union { unsigned u[4]; bf16x8 v; } pw;
        pw.u[0] = s0[0]; pw.u[1] = s1[0]; pw.u[2] = s0[1]; pw.u[3] = s1[1];
        pa[f * 2 + cc] = pw.v;
      }
    }

    // PV
    __builtin_amdgcn_s_setprio(1);
#pragma unroll
    for (int c = 0; c < 4; ++c) {
      o0 = __builtin_amdgcn_mfma_f32_32x32x16_bf16(pa[c], vf0[c], o0, 0, 0, 0);
      o1 = __builtin_amdgcn_mfma_f32_32x32x16_bf16(pa[c], vf1[c], o1, 0, 0, 0);
    }
    __builtin_amdgcn_s_setprio(0);

    asm volatile("" ::: "memory");
    __builtin_amdgcn_sched_barrier(0);
    __builtin_amdgcn_s_barrier();   // reads of tile t done -> next stage may overwrite
  };

  for (int tt = 0; tt < 32; tt += 2) {
    body(tt + 0, 0);
    body(tt + 1, 1);
  }

  // per-half lsum finalize (cross-hi reduce)
  float lsum = (la0 + la1) + (la2 + la3);
  lsum += __shfl_xor(lsum, 32);

  // combine halves via LDS (exact: no-max softmax partials are additive)
  __syncthreads();  // drains wrap-prefetch vmcnt; all tile reads done
  float* cbO0 = (float*)&Ks[0][0][0];  // 32 KB
  float* cbO1 = (float*)&Vs[0][0][0];  // 32 KB
  float* cbL  = (float*)&Qs[0];        // 1 KB of 16
  int cbase = (qw * 64 + lane) * 32;
  int lx = lane & 31;
  if (grp == 1) {
#pragma unroll
    for (int r = 0; r < 16; ++r) {
      cbO0[cbase + (r ^ lx)] = o0[r];
      cbO1[cbase + (r ^ lx)] = o1[r];
    }
    cbL[qw * 64 + lane] = lsum;
  }
  __syncthreads();
  if (grp == 0) {
#pragma unroll
    for (int r = 0; r < 16; ++r) {
      o0[r] += cbO0[cbase + (r ^ lx)];
      o1[r] += cbO1[cbase + (r ^ lx)];
    }
    lsum += cbL[qw * 64 + lane];
    float inv = 1.f / lsum;
#pragma unroll
    for (int r = 0; r < 16; ++r) {
      int qr = (r & 3) + 8 * (r >> 2) + 4 * hi;
      float ir = __shfl(inv, qr + (lane & 32));
      size_t row = q0 + qw * 32 + qr;
      Aout[row * DIM + h * HD + l31]      = f2bf(o0[r] * ir);
      Aout[row * DIM + h * HD + 32 + l31] = f2bf(o1[r] * ir);
    }
  }
}

extern "C" void kernel_launch(void* const* d_in, const int* in_sizes, int n_in,
                              void* d_out, int out_size, void* d_ws, size_t ws_size,
                              hipStream_t stream) {
  (void)in_sizes; (void)n_in; (void)out_size; (void)ws_size;
  const float* X  = (const float*)d_in[0];
  const float* wq = (const float*)d_in[1];
  const float* bq = (const float*)d_in[2];
  const float* wk = (const float*)d_in[3];
  const float* wv = (const float*)d_in[4];
  const float* bv = (const float*)d_in[5];
  const float* wo = (const float*)d_in[6];
  const float* bo = (const float*)d_in[7];

  char* ws = (char*)d_ws;
  const size_t SZ_XD  = (size_t)SEQ * DIM * 2;      // 8 MB
  const size_t SZ_W   = (size_t)DIM * DIM * 2;      // 2 MB
  const size_t SZ_QKV = (size_t)SEQ * QKVSTR * 2;   // 24 MB
  unsigned short* Xb   = (unsigned short*)(ws);                    // reused as Ab
  unsigned short* Wqkv = (unsigned short*)(ws + SZ_XD);            // [3072][1024]
  unsigned short* Wob  = (unsigned short*)(ws + SZ_XD + 3 * SZ_W);
  unsigned short* QKVb = (unsigned short*)(ws + SZ_XD + 4 * SZ_W); // [4096][3072]
  unsigned short* Vtb  = (unsigned short*)(ws + SZ_XD + 4 * SZ_W + SZ_QKV);
  unsigned short* Ab   = Xb;

  const float QSCALE = 0.125f * 1.44269504088896f;  // fold 1/sqrt(hd) * log2(e) into Wq/bq

  // one fused cast launch: 1048576 groups of 8 -> 4096 blocks
  cast_all_kernel<<<4096, 256, 0, stream>>>(X, wq, wk, wv, wo, Xb, Wqkv, Wob, QSCALE);

  // fused QKV projection: [4096][3072] bf16; V section written transposed to Vtb
  gemm_bt_kernel<1, 0><<<dim3(QKVSTR / 128, SEQ / 128), 256, 0, stream>>>(
      Xb, Wqkv, bq, bv, QSCALE, QKVb, Vtb, SEQ, QKVSTR, DIM);

  attn_kernel<<<SEQ / 128 * NH, 512, 0, stream>>>(QKVb, Vtb, Ab);

  // output projection (f32 out)
  gemm_bt_kernel<2, 1><<<dim3(DIM / 128, SEQ / 128), 256, 0, stream>>>(
      Ab, Wob, bo, nullptr, 1.f, d_out, nullptr, SEQ, DIM, DIM);
}

// Round 14
// 162.049 us; speedup vs baseline: 1.0610x; 1.0224x over previous
//
#include <hip/hip_runtime.h>

#define SEQ 4096
#define DIM 1024
#define NH 16
#define HD 64
#define QKVSTR 3072

typedef __attribute__((ext_vector_type(8))) short bf16x8;
typedef __attribute__((ext_vector_type(4))) float f32x4;
typedef __attribute__((ext_vector_type(16))) float f32x16;
typedef __attribute__((ext_vector_type(4))) unsigned int uint4v;

__device__ __forceinline__ unsigned short f2bf(float f) {
  unsigned int b = __float_as_uint(f);
  b = b + 0x7fffu + ((b >> 16) & 1u);
  return (unsigned short)(b >> 16);
}

__device__ __forceinline__ unsigned int cvt_pk_bf16(float lo, float hi) {
  unsigned int r;
  asm("v_cvt_pk_bf16_f32 %0, %1, %2" : "=v"(r) : "v"(lo), "v"(hi));
  return r;
}

__device__ __forceinline__ float fast_exp2(float x) {
#if __has_builtin(__builtin_amdgcn_exp2f)
  return __builtin_amdgcn_exp2f(x);
#else
  float r; asm("v_exp_f32 %0, %1" : "=v"(r) : "v"(x)); return r;
#endif
}

typedef __attribute__((address_space(3))) unsigned int lds_uint;
typedef __attribute__((address_space(1))) const unsigned int global_uint;

__device__ __forceinline__ void gload_lds16(const void* g, void* l) {
  __builtin_amdgcn_global_load_lds((global_uint*)g, (lds_uint*)l, 16, 0, 0);
}

// ---------------- fused cast fp32 -> bf16 for all 5 tensors (1 launch) ----------------
__global__ __launch_bounds__(256) void cast_all_kernel(
    const float* __restrict__ X, const float* __restrict__ wq, const float* __restrict__ wk,
    const float* __restrict__ wv, const float* __restrict__ wo,
    unsigned short* __restrict__ Xb, unsigned short* __restrict__ Wqkv,
    unsigned short* __restrict__ Wob, float qscale) {
  int i = blockIdx.x * 256 + threadIdx.x;
  const float* src;
  unsigned short* dst;
  float sc = 1.f;
  if (i < 524288) { src = X + (size_t)i * 8; dst = Xb + (size_t)i * 8; }
  else if (i < 655360) { int j = i - 524288; src = wq + (size_t)j * 8; dst = Wqkv + (size_t)j * 8; sc = qscale; }
  else if (i < 786432) { int j = i - 655360; src = wk + (size_t)j * 8; dst = Wqkv + 1048576 + (size_t)j * 8; }
  else if (i < 917504) { int j = i - 786432; src = wv + (size_t)j * 8; dst = Wqkv + 2097152 + (size_t)j * 8; }
  else { int j = i - 917504; src = wo + (size_t)j * 8; dst = Wob + (size_t)j * 8; }
  const float4* p = (const float4*)src;
  float4 x0 = p[0], x1 = p[1];
  union { unsigned short u[8]; uint4v v; } o;
  o.u[0] = f2bf(x0.x * sc); o.u[1] = f2bf(x0.y * sc);
  o.u[2] = f2bf(x0.z * sc); o.u[3] = f2bf(x0.w * sc);
  o.u[4] = f2bf(x1.x * sc); o.u[5] = f2bf(x1.y * sc);
  o.u[6] = f2bf(x1.z * sc); o.u[7] = f2bf(x1.w * sc);
  *(uint4v*)dst = o.v;
}

// ---------------- GEMM: C[M,N] = A[M,K](bf16) @ B[N,K]^T(bf16) (+bias) ----------------
// T3-minimum 2-phase + counted vmcnt + bijective XCD swizzle (R10-proven).
// BN: N-tile (128 or 64). BN=64 -> 2x blocks (fixes 1-block/CU out-proj occupancy).
// BIASMODE==1 additionally writes the V section (col>=2048) TRANSPOSED into Vt.
template<int BIASMODE, int OUT_F32, int BN>
__global__ __launch_bounds__(256) void gemm_bt_kernel(
    const unsigned short* __restrict__ A, const unsigned short* __restrict__ B,
    const float* __restrict__ b0, const float* __restrict__ b1, float qscale,
    void* __restrict__ Cout, unsigned short* __restrict__ Vt, int M, int N, int K) {
  constexpr int NF = BN / 32;          // n-frags per wave
  __shared__ unsigned short As[2][128 * 32];
  __shared__ unsigned short Bs[2][BN * 32];
  int tid = threadIdx.x;
  int wave = tid >> 6, lane = tid & 63;
  int g = lane >> 4, lc = lane & 15;
  int wm = wave >> 1, wn = wave & 1;

  int gx = gridDim.x;
  int wgid = blockIdx.y * gx + blockIdx.x;
  int cpx = (gx * gridDim.y) >> 3;
  int sw = (wgid & 7) * cpx + (wgid >> 3);
  int m0 = (sw / gx) * 128, n0 = (sw % gx) * BN;

  int ch0 = wave * 64 + lane;
  int r0 = ch0 >> 2, cb0 = ch0 & 3;
  int ch1 = 256 + ch0;
  int r1 = ch1 >> 2, cb1 = ch1 & 3;
  const unsigned short* Ar0 = A + (size_t)(m0 + r0) * K + cb0 * 8;
  const unsigned short* Ar1 = A + (size_t)(m0 + r1) * K + cb1 * 8;
  const unsigned short* Br0 = B + (size_t)(n0 + r0) * K + cb0 * 8;
  const unsigned short* Br1 = B + (size_t)(n0 + r1) * K + cb1 * 8;  // unused if BN==64
  unsigned short* sAlo[2] = { &As[0][(wave * 64) * 8],       &As[1][(wave * 64) * 8] };
  unsigned short* sAhi[2] = { &As[0][(256 + wave * 64) * 8], &As[1][(256 + wave * 64) * 8] };
  unsigned short* sBlo[2] = { &Bs[0][(wave * 64) * 8],       &Bs[1][(wave * 64) * 8] };
  unsigned short* sBhi[2] = { &Bs[0][(256 + wave * 64) * 8], &Bs[1][(256 + wave * 64) * 8] };

  f32x4 acc[4][NF] = {};

  gload_lds16(Ar0, sAlo[0]);
  gload_lds16(Ar1, sAhi[0]);
  gload_lds16(Br0, sBlo[0]);
  if (BN == 128) gload_lds16(Br1, sBhi[0]);

  int cur = 0;
  for (int k0 = 0; k0 < K; k0 += 32) {
    {
      int kn = (k0 + 32 < K) ? (k0 + 32) : 0;
      int nb = cur ^ 1;
      gload_lds16(Ar0 + kn, sAlo[nb]);
      gload_lds16(Ar1 + kn, sAhi[nb]);
      gload_lds16(Br0 + kn, sBlo[nb]);
      if (BN == 128) gload_lds16(Br1 + kn, sBhi[nb]);
    }
    if (BN == 128) {
      asm volatile("s_waitcnt vmcnt(4)" ::: "memory");
    } else {
      asm volatile("s_waitcnt vmcnt(3)" ::: "memory");
    }
    __builtin_amdgcn_sched_barrier(0);
    __builtin_amdgcn_s_barrier();
    __builtin_amdgcn_sched_barrier(0);

    bf16x8 af[4], bfr[NF];
    for (int mf = 0; mf < 4; ++mf)
      af[mf] = *(const bf16x8*)&As[cur][(wm * 64 + mf * 16 + lc) * 32 + g * 8];
    for (int nf = 0; nf < NF; ++nf)
      bfr[nf] = *(const bf16x8*)&Bs[cur][(wn * (BN / 2) + nf * 16 + lc) * 32 + g * 8];
    for (int mf = 0; mf < 4; ++mf)
      for (int nf = 0; nf < NF; ++nf)
        acc[mf][nf] = __builtin_amdgcn_mfma_f32_16x16x32_bf16(af[mf], bfr[nf], acc[mf][nf], 0, 0, 0);

    asm volatile("" ::: "memory");
    __builtin_amdgcn_sched_barrier(0);
    __builtin_amdgcn_s_barrier();
    cur ^= 1;
  }

  for (int nf = 0; nf < NF; ++nf) {
    int col = n0 + wn * (BN / 2) + nf * 16 + lc;
    float bias = 0.f;
    if (BIASMODE == 1) {
      int sect = col >> 10, cc = col & 1023;
      bias = (sect == 0) ? b0[cc] * qscale : ((sect == 2) ? b1[cc] : 0.f);
    } else if (BIASMODE == 2) {
      bias = b0[col];
    }
    for (int mf = 0; mf < 4; ++mf) {
      int row = m0 + wm * 64 + mf * 16 + g * 4;
      for (int r = 0; r < 4; ++r) {
        float v = acc[mf][nf][r] + bias;
        if (OUT_F32) {
          ((float*)Cout)[(size_t)(row + r) * N + col] = v;
        } else if (BIASMODE == 1 && col >= 2048) {
          Vt[(size_t)(col - 2048) * SEQ + row + r] = f2bf(v);
        } else {
          ((unsigned short*)Cout)[(size_t)(row + r) * N + col] = f2bf(v);
        }
      }
    }
  }
}

// ---------------- flash attention: 8-wave in-block kv-split x2 (R13-proven) ----------------
__global__ __launch_bounds__(512, 1) void attn_kernel(
    const unsigned short* __restrict__ QKV, const unsigned short* __restrict__ Vt,
    unsigned short* __restrict__ Aout) {
  __shared__ unsigned short Qs[128 * 64];        // 16 KB
  __shared__ unsigned short Ks[2][2][64 * 64];   // [grp][buf] 32 KB
  __shared__ unsigned short Vs[2][2][64 * 64];   // 32 KB  (total 80 KB -> 2 blocks/CU)
  int tid = threadIdx.x;
  int w = tid >> 6, lane = tid & 63;
  int hi = lane >> 5, l31 = lane & 31;
  int qw = w & 3, grp = w >> 2;

  // XCD swizzle: 512 blocks, 8 XCDs -> XCD x owns heads 2x..2x+1 (K/V fit 4MB L2)
  int bid = blockIdx.x;
  int swz = (bid & 7) * 64 + (bid >> 3);
  int h = swz >> 5;
  int q0 = (swz & 31) * 128;

  const unsigned short* Qg = QKV + h * HD;
  const unsigned short* Kg = QKV + DIM + h * HD;
  const unsigned short* Vg = Vt + (size_t)(h * HD) * SEQ;
  int kvbase = grp * (SEQ / 2);

  int ch0 = qw * 64 + lane;
  int r0s = ch0 >> 3, d0s = (ch0 & 7) ^ (r0s & 7);
  int ch1 = 256 + ch0;
  int r1s = ch1 >> 3, d1s = (ch1 & 7) ^ (r1s & 7);
  size_t koff0 = (size_t)r0s * QKVSTR + d0s * 8;
  size_t koff1 = (size_t)r1s * QKVSTR + d1s * 8;
  size_t voff0 = (size_t)r0s * SEQ + d0s * 8;
  size_t voff1 = (size_t)r1s * SEQ + d1s * 8;
  unsigned short* sKlo[2] = { &Ks[grp][0][(qw * 64) * 8],       &Ks[grp][1][(qw * 64) * 8] };
  unsigned short* sKhi[2] = { &Ks[grp][0][(256 + qw * 64) * 8], &Ks[grp][1][(256 + qw * 64) * 8] };
  unsigned short* sVlo[2] = { &Vs[grp][0][(qw * 64) * 8],       &Vs[grp][1][(qw * 64) * 8] };
  unsigned short* sVhi[2] = { &Vs[grp][0][(256 + qw * 64) * 8], &Vs[grp][1][(256 + qw * 64) * 8] };

  // stage Q [128][64]: 1024 chunks by 8 waves, XOR-swizzled via global source
  for (int c = 0; c < 2; ++c) {
    int chunk = c * 512 + w * 64 + lane;
    int row = chunk >> 3, pos = chunk & 7;
    int db = pos ^ (row & 7);
    gload_lds16(Qg + (size_t)(q0 + row) * QKVSTR + db * 8, Qs + (c * 512 + w * 64) * 8);
  }
  // stage this group's K/V tile 0
  {
    const unsigned short* Kt = Kg + (size_t)kvbase * QKVSTR;
    const unsigned short* Vtt = Vg + kvbase;
    gload_lds16(Kt + koff0, sKlo[0]);
    gload_lds16(Kt + koff1, sKhi[0]);
    gload_lds16(Vtt + voff0, sVlo[0]);
    gload_lds16(Vtt + voff1, sVhi[0]);
  }
  asm volatile("s_waitcnt vmcnt(4)" ::: "memory");  // Q landed; tile0 in flight
  __builtin_amdgcn_sched_barrier(0);
  __builtin_amdgcn_s_barrier();

  // Q fragments (B-operand: col q = l31, k = d); both groups read same q-rows
  bf16x8 qf[4];
  {
    int qrow = qw * 32 + l31;
    for (int dc = 0; dc < 4; ++dc) {
      int pos = 2 * dc + hi;
      qf[dc] = *(const bf16x8*)&Qs[qrow * 64 + (pos ^ (qrow & 7)) * 8];
    }
  }

  // hoisted LDS byte offsets for kf/vf (f=1 row+32 keeps &7 -> +4096B imm)
  int offb[4];
#pragma unroll
  for (int dc = 0; dc < 4; ++dc)
    offb[dc] = l31 * 128 + (((2 * dc + hi) ^ (l31 & 7)) * 16);
  const char* KbA = (const char*)&Ks[grp][0][0];
  const char* KbB = (const char*)&Ks[grp][1][0];
  const char* VbA = (const char*)&Vs[grp][0][0];
  const char* VbB = (const char*)&Vs[grp][1][0];

  f32x16 o0 = {}, o1 = {};
  float la0 = 0.f, la1 = 0.f, la2 = 0.f, la3 = 0.f;

  auto body = [&](int t, int CUR) {
    int NB = CUR ^ 1;
    int kvn = kvbase + (((t + 1) & 31) << 6);
    const unsigned short* Kt = Kg + (size_t)kvn * QKVSTR;
    const unsigned short* Vtt = Vg + kvn;
    gload_lds16(Kt + koff0, sKlo[NB]);
    gload_lds16(Kt + koff1, sKhi[NB]);
    gload_lds16(Vtt + voff0, sVlo[NB]);
    gload_lds16(Vtt + voff1, sVhi[NB]);
    asm volatile("s_waitcnt vmcnt(4)" ::: "memory");  // tile t resident (this wave)
    __builtin_amdgcn_sched_barrier(0);
    __builtin_amdgcn_s_barrier();                     // tile t resident (all waves)
    __builtin_amdgcn_sched_barrier(0);

    const char* Kb = CUR ? KbB : KbA;
    const char* Vb = CUR ? VbB : VbA;
    bf16x8 kf0[4], kf1[4];
#pragma unroll
    for (int dc = 0; dc < 4; ++dc) {
      kf0[dc] = *(const bf16x8*)(Kb + offb[dc]);
      kf1[dc] = *(const bf16x8*)(Kb + offb[dc] + 4096);
    }
    f32x16 st0 = {}, st1 = {};
    __builtin_amdgcn_s_setprio(1);
#pragma unroll
    for (int dc = 0; dc < 4; ++dc) {
      st0 = __builtin_amdgcn_mfma_f32_32x32x16_bf16(kf0[dc], qf[dc], st0, 0, 0, 0);
      st1 = __builtin_amdgcn_mfma_f32_32x32x16_bf16(kf1[dc], qf[dc], st1, 0, 0, 0);
    }
    __builtin_amdgcn_s_setprio(0);

    bf16x8 vf0[4], vf1[4];
#pragma unroll
    for (int c = 0; c < 4; ++c) {
      vf0[c] = *(const bf16x8*)(Vb + offb[c]);
      vf1[c] = *(const bf16x8*)(Vb + offb[c] + 4096);
    }

    float p0[16], p1[16];
#pragma unroll
    for (int r = 0; r < 16; r += 4) {
      p0[r] = fast_exp2(st0[r]); p0[r + 1] = fast_exp2(st0[r + 1]);
      p0[r + 2] = fast_exp2(st0[r + 2]); p0[r + 3] = fast_exp2(st0[r + 3]);
      la0 += p0[r]; la1 += p0[r + 1]; la2 += p0[r + 2]; la3 += p0[r + 3];
    }
#pragma unroll
    for (int r = 0; r < 16; r += 4) {
      p1[r] = fast_exp2(st1[r]); p1[r + 1] = fast_exp2(st1[r + 1]);
      p1[r + 2] = fast_exp2(st1[r + 2]); p1[r + 3] = fast_exp2(st1[r + 3]);
      la0 += p1[r]; la1 += p1[r + 1]; la2 += p1[r + 2]; la3 += p1[r + 3];
    }

    bf16x8 pa[4];
#pragma unroll
    for (int f = 0; f < 2; ++f) {
      const float* pp = f ? p1 : p0;
#pragma unroll
      for (int cc = 0; cc < 2; ++cc) {
        unsigned uLO0 = cvt_pk_bf16(pp[8 * cc + 0], pp[8 * cc + 1]);
        unsigned uLO1 = cvt_pk_bf16(pp[8 * cc + 2], pp[8 * cc + 3]);
        unsigned uHI0 = cvt_pk_bf16(pp[8 * cc + 4], pp[8 * cc + 5]);
        unsigned uHI1 = cvt_pk_bf16(pp[8 * cc + 6], pp[8 * cc + 7]);
        auto s0 = __builtin_amdgcn_permlane32_swap(uLO0, uHI0, false, false);
        auto s1 = __builtin_amdgcn_permlane32_swap(uLO1, uHI1, false, false);
        union { unsigned u[4]; bf16x8 v; } pw;
        pw.u[0] = s0[0]; pw.u[1] = s1[0]; pw.u[2] = s0[1]; pw.u[3] = s1[1];
        pa[f * 2 + cc] = pw.v;
      }
    }

    __builtin_amdgcn_s_setprio(1);
#pragma unroll
    for (int c = 0; c < 4; ++c) {
      o0 = __builtin_amdgcn_mfma_f32_32x32x16_bf16(pa[c], vf0[c], o0, 0, 0, 0);
      o1 = __builtin_amdgcn_mfma_f32_32x32x16_bf16(pa[c], vf1[c], o1, 0, 0, 0);
    }
    __builtin_amdgcn_s_setprio(0);

    asm volatile("" ::: "memory");
    __builtin_amdgcn_sched_barrier(0);
    __builtin_amdgcn_s_barrier();   // reads of tile t done -> next stage may overwrite
  };

  for (int tt = 0; tt < 32; tt += 2) {
    body(tt + 0, 0);
    body(tt + 1, 1);
  }

  // per-half lsum finalize (cross-hi reduce)
  float lsum = (la0 + la1) + (la2 + la3);
  lsum += __shfl_xor(lsum, 32);

  // combine halves via LDS (exact: no-max softmax partials are additive)
  __syncthreads();  // drains wrap-prefetch vmcnt; all tile reads done
  float* cbO0 = (float*)&Ks[0][0][0];  // 32 KB
  float* cbO1 = (float*)&Vs[0][0][0];  // 32 KB
  float* cbL  = (float*)&Qs[0];        // 1 KB of 16
  int cbase = (qw * 64 + lane) * 32;
  int lx = lane & 31;
  if (grp == 1) {
#pragma unroll
    for (int r = 0; r < 16; ++r) {
      cbO0[cbase + (r ^ lx)] = o0[r];
      cbO1[cbase + (r ^ lx)] = o1[r];
    }
    cbL[qw * 64 + lane] = lsum;
  }
  __syncthreads();
  if (grp == 0) {
#pragma unroll
    for (int r = 0; r < 16; ++r) {
      o0[r] += cbO0[cbase + (r ^ lx)];
      o1[r] += cbO1[cbase + (r ^ lx)];
    }
    lsum += cbL[qw * 64 + lane];
    float inv = 1.f / lsum;
#pragma unroll
    for (int r = 0; r < 16; ++r) {
      int qr = (r & 3) + 8 * (r >> 2) + 4 * hi;
      float ir = __shfl(inv, qr + (lane & 32));
      size_t row = q0 + qw * 32 + qr;
      Aout[row * DIM + h * HD + l31]      = f2bf(o0[r] * ir);
      Aout[row * DIM + h * HD + 32 + l31] = f2bf(o1[r] * ir);
    }
  }
}

extern "C" void kernel_launch(void* const* d_in, const int* in_sizes, int n_in,
                              void* d_out, int out_size, void* d_ws, size_t ws_size,
                              hipStream_t stream) {
  (void)in_sizes; (void)n_in; (void)out_size; (void)ws_size;
  const float* X  = (const float*)d_in[0];
  const float* wq = (const float*)d_in[1];
  const float* bq = (const float*)d_in[2];
  const float* wk = (const float*)d_in[3];
  const float* wv = (const float*)d_in[4];
  const float* bv = (const float*)d_in[5];
  const float* wo = (const float*)d_in[6];
  const float* bo = (const float*)d_in[7];

  char* ws = (char*)d_ws;
  const size_t SZ_XD  = (size_t)SEQ * DIM * 2;      // 8 MB
  const size_t SZ_W   = (size_t)DIM * DIM * 2;      // 2 MB
  const size_t SZ_QKV = (size_t)SEQ * QKVSTR * 2;   // 24 MB
  unsigned short* Xb   = (unsigned short*)(ws);                    // reused as Ab
  unsigned short* Wqkv = (unsigned short*)(ws + SZ_XD);            // [3072][1024]
  unsigned short* Wob  = (unsigned short*)(ws + SZ_XD + 3 * SZ_W);
  unsigned short* QKVb = (unsigned short*)(ws + SZ_XD + 4 * SZ_W); // [4096][3072]
  unsigned short* Vtb  = (unsigned short*)(ws + SZ_XD + 4 * SZ_W + SZ_QKV);
  unsigned short* Ab   = Xb;

  const float QSCALE = 0.125f * 1.44269504088896f;  // fold 1/sqrt(hd) * log2(e) into Wq/bq

  // one fused cast launch: 1048576 groups of 8 -> 4096 blocks
  cast_all_kernel<<<4096, 256, 0, stream>>>(X, wq, wk, wv, wo, Xb, Wqkv, Wob, QSCALE);

  // fused QKV projection: [4096][3072] bf16; V section written transposed to Vtb
  gemm_bt_kernel<1, 0, 128><<<dim3(QKVSTR / 128, SEQ / 128), 256, 0, stream>>>(
      Xb, Wqkv, bq, bv, QSCALE, QKVb, Vtb, SEQ, QKVSTR, DIM);

  attn_kernel<<<SEQ / 128 * NH, 512, 0, stream>>>(QKVb, Vtb, Ab);

  // output projection (f32 out): 128x64 tiles -> 512 blocks = 2/CU (was 1/CU)
  gemm_bt_kernel<2, 1, 64><<<dim3(DIM / 64, SEQ / 128), 256, 0, stream>>>(
      Ab, Wob, bo, nullptr, 1.f, d_out, nullptr, SEQ, DIM, DIM);
}

// Round 15
// 159.746 us; speedup vs baseline: 1.0763x; 1.0144x over previous
//
#include <hip/hip_runtime.h>

#define SEQ 4096
#define DIM 1024
#define NH 16
#define HD 64
#define QKVSTR 3072

typedef __attribute__((ext_vector_type(8))) short bf16x8;
typedef __attribute__((ext_vector_type(4))) float f32x4;
typedef __attribute__((ext_vector_type(16))) float f32x16;
typedef __attribute__((ext_vector_type(4))) unsigned int uint4v;

__device__ __forceinline__ unsigned short f2bf(float f) {
  unsigned int b = __float_as_uint(f);
  b = b + 0x7fffu + ((b >> 16) & 1u);
  return (unsigned short)(b >> 16);
}

__device__ __forceinline__ unsigned int cvt_pk_bf16(float lo, float hi) {
  unsigned int r;
  asm("v_cvt_pk_bf16_f32 %0, %1, %2" : "=v"(r) : "v"(lo), "v"(hi));
  return r;
}

__device__ __forceinline__ float fast_exp2(float x) {
#if __has_builtin(__builtin_amdgcn_exp2f)
  return __builtin_amdgcn_exp2f(x);
#else
  float r; asm("v_exp_f32 %0, %1" : "=v"(r) : "v"(x)); return r;
#endif
}

typedef __attribute__((address_space(3))) unsigned int lds_uint;
typedef __attribute__((address_space(1))) const unsigned int global_uint;

__device__ __forceinline__ void gload_lds16(const void* g, void* l) {
  __builtin_amdgcn_global_load_lds((global_uint*)g, (lds_uint*)l, 16, 0, 0);
}

// ---------------- fused cast fp32 -> bf16 for all 5 tensors (1 launch) ----------------
__global__ __launch_bounds__(256) void cast_all_kernel(
    const float* __restrict__ X, const float* __restrict__ wq, const float* __restrict__ wk,
    const float* __restrict__ wv, const float* __restrict__ wo,
    unsigned short* __restrict__ Xb, unsigned short* __restrict__ Wqkv,
    unsigned short* __restrict__ Wob, float qscale) {
  int i = blockIdx.x * 256 + threadIdx.x;
  const float* src;
  unsigned short* dst;
  float sc = 1.f;
  if (i < 524288) { src = X + (size_t)i * 8; dst = Xb + (size_t)i * 8; }
  else if (i < 655360) { int j = i - 524288; src = wq + (size_t)j * 8; dst = Wqkv + (size_t)j * 8; sc = qscale; }
  else if (i < 786432) { int j = i - 655360; src = wk + (size_t)j * 8; dst = Wqkv + 1048576 + (size_t)j * 8; }
  else if (i < 917504) { int j = i - 786432; src = wv + (size_t)j * 8; dst = Wqkv + 2097152 + (size_t)j * 8; }
  else { int j = i - 917504; src = wo + (size_t)j * 8; dst = Wob + (size_t)j * 8; }
  const float4* p = (const float4*)src;
  float4 x0 = p[0], x1 = p[1];
  union { unsigned short u[8]; uint4v v; } o;
  o.u[0] = f2bf(x0.x * sc); o.u[1] = f2bf(x0.y * sc);
  o.u[2] = f2bf(x0.z * sc); o.u[3] = f2bf(x0.w * sc);
  o.u[4] = f2bf(x1.x * sc); o.u[5] = f2bf(x1.y * sc);
  o.u[6] = f2bf(x1.z * sc); o.u[7] = f2bf(x1.w * sc);
  *(uint4v*)dst = o.v;
}

// ---------------- GEMM: C[M,N] = A[M,K](bf16) @ B[N,K]^T(bf16) (+bias) ----------------
// 2-DEEP prefetch, 3 LDS buffers: at iter i stage tile i+2, vmcnt(2*loads) ->
// tile i resident while i+1/i+2 stay in flight. Same one-barrier write/read
// separation as the proven 2-buffer template. Bijective XCD swizzle.
// BIASMODE==1 additionally writes the V section (col>=2048) TRANSPOSED into Vt.
template<int BIASMODE, int OUT_F32, int BN>
__global__ __launch_bounds__(256) void gemm_bt_kernel(
    const unsigned short* __restrict__ A, const unsigned short* __restrict__ B,
    const float* __restrict__ b0, const float* __restrict__ b1, float qscale,
    void* __restrict__ Cout, unsigned short* __restrict__ Vt, int M, int N, int K) {
  constexpr int NF = BN / 32;          // n-frags per wave
  __shared__ unsigned short As[3][128 * 32];
  __shared__ unsigned short Bs[3][BN * 32];
  int tid = threadIdx.x;
  int wave = tid >> 6, lane = tid & 63;
  int g = lane >> 4, lc = lane & 15;
  int wm = wave >> 1, wn = wave & 1;

  int gx = gridDim.x;
  int wgid = blockIdx.y * gx + blockIdx.x;
  int cpx = (gx * gridDim.y) >> 3;
  int sw = (wgid & 7) * cpx + (wgid >> 3);
  int m0 = (sw / gx) * 128, n0 = (sw % gx) * BN;

  int ch0 = wave * 64 + lane;
  int r0 = ch0 >> 2, cb0 = ch0 & 3;
  int ch1 = 256 + ch0;
  int r1 = ch1 >> 2, cb1 = ch1 & 3;
  const unsigned short* Ar0 = A + (size_t)(m0 + r0) * K + cb0 * 8;
  const unsigned short* Ar1 = A + (size_t)(m0 + r1) * K + cb1 * 8;
  const unsigned short* Br0 = B + (size_t)(n0 + r0) * K + cb0 * 8;
  const unsigned short* Br1 = B + (size_t)(n0 + r1) * K + cb1 * 8;  // unused if BN==64

  unsigned short* sAlo[3] = { &As[0][(wave * 64) * 8], &As[1][(wave * 64) * 8], &As[2][(wave * 64) * 8] };
  unsigned short* sAhi[3] = { &As[0][(256 + wave * 64) * 8], &As[1][(256 + wave * 64) * 8], &As[2][(256 + wave * 64) * 8] };
  unsigned short* sBlo[3] = { &Bs[0][(wave * 64) * 8], &Bs[1][(wave * 64) * 8], &Bs[2][(wave * 64) * 8] };
  unsigned short* sBhi[3] = { &Bs[0][(256 + wave * 64) * 8], &Bs[1][(256 + wave * 64) * 8], &Bs[2][(256 + wave * 64) * 8] };

  f32x4 acc[4][NF] = {};

  auto stage = [&](int kn, int b) {
    gload_lds16(Ar0 + kn, sAlo[b]);
    gload_lds16(Ar1 + kn, sAhi[b]);
    gload_lds16(Br0 + kn, sBlo[b]);
    if (BN == 128) gload_lds16(Br1 + kn, sBhi[b]);
  };

  auto compute = [&](int b) {
    bf16x8 af[4], bfr[NF];
    for (int mf = 0; mf < 4; ++mf)
      af[mf] = *(const bf16x8*)&As[b][(wm * 64 + mf * 16 + lc) * 32 + g * 8];
    for (int nf = 0; nf < NF; ++nf)
      bfr[nf] = *(const bf16x8*)&Bs[b][(wn * (BN / 2) + nf * 16 + lc) * 32 + g * 8];
    for (int mf = 0; mf < 4; ++mf)
      for (int nf = 0; nf < NF; ++nf)
        acc[mf][nf] = __builtin_amdgcn_mfma_f32_16x16x32_bf16(af[mf], bfr[nf], acc[mf][nf], 0, 0, 0);
  };

  const int NT = K / 32;  // 32 K-steps
  auto step = [&](int i, int CUR, int STG) {
    int kn = (i + 2 < NT) ? (i + 2) * 32 : 0;  // wrap: dummy reload of k=0
    stage(kn, STG);
    if (BN == 128) {
      asm volatile("s_waitcnt vmcnt(8)" ::: "memory");   // tile i resident; i+1,i+2 in flight
    } else {
      asm volatile("s_waitcnt vmcnt(6)" ::: "memory");
    }
    __builtin_amdgcn_sched_barrier(0);
    __builtin_amdgcn_s_barrier();
    __builtin_amdgcn_sched_barrier(0);
    compute(CUR);
    asm volatile("" ::: "memory");
    __builtin_amdgcn_sched_barrier(0);
    __builtin_amdgcn_s_barrier();   // reads of tile i done -> buf may be overwritten next iter
  };

  // prologue: stage tiles 0,1 into bufs 0,1 (2*loads outstanding)
  stage(0, 0);
  stage(32, 1);

  // NT = 32 = 3*10 + 2; manual unroll keeps buffer indices compile-time
  for (int ii = 0; ii < 30; ii += 3) {
    step(ii + 0, 0, 2);
    step(ii + 1, 1, 0);
    step(ii + 2, 2, 1);
  }
  step(30, 0, 2);
  step(31, 1, 0);

  for (int nf = 0; nf < NF; ++nf) {
    int col = n0 + wn * (BN / 2) + nf * 16 + lc;
    float bias = 0.f;
    if (BIASMODE == 1) {
      int sect = col >> 10, cc = col & 1023;
      bias = (sect == 0) ? b0[cc] * qscale : ((sect == 2) ? b1[cc] : 0.f);
    } else if (BIASMODE == 2) {
      bias = b0[col];
    }
    for (int mf = 0; mf < 4; ++mf) {
      int row = m0 + wm * 64 + mf * 16 + g * 4;
      for (int r = 0; r < 4; ++r) {
        float v = acc[mf][nf][r] + bias;
        if (OUT_F32) {
          ((float*)Cout)[(size_t)(row + r) * N + col] = v;
        } else if (BIASMODE == 1 && col >= 2048) {
          Vt[(size_t)(col - 2048) * SEQ + row + r] = f2bf(v);
        } else {
          ((unsigned short*)Cout)[(size_t)(row + r) * N + col] = f2bf(v);
        }
      }
    }
  }
}

// ---------------- flash attention: 8-wave in-block kv-split x2 (R13-proven, unchanged) ----------------
__global__ __launch_bounds__(512, 1) void attn_kernel(
    const unsigned short* __restrict__ QKV, const unsigned short* __restrict__ Vt,
    unsigned short* __restrict__ Aout) {
  __shared__ unsigned short Qs[128 * 64];        // 16 KB
  __shared__ unsigned short Ks[2][2][64 * 64];   // [grp][buf] 32 KB
  __shared__ unsigned short Vs[2][2][64 * 64];   // 32 KB  (total 80 KB -> 2 blocks/CU)
  int tid = threadIdx.x;
  int w = tid >> 6, lane = tid & 63;
  int hi = lane >> 5, l31 = lane & 31;
  int qw = w & 3, grp = w >> 2;

  // XCD swizzle: 512 blocks, 8 XCDs -> XCD x owns heads 2x..2x+1 (K/V fit 4MB L2)
  int bid = blockIdx.x;
  int swz = (bid & 7) * 64 + (bid >> 3);
  int h = swz >> 5;
  int q0 = (swz & 31) * 128;

  const unsigned short* Qg = QKV + h * HD;
  const unsigned short* Kg = QKV + DIM + h * HD;
  const unsigned short* Vg = Vt + (size_t)(h * HD) * SEQ;
  int kvbase = grp * (SEQ / 2);

  int ch0 = qw * 64 + lane;
  int r0s = ch0 >> 3, d0s = (ch0 & 7) ^ (r0s & 7);
  int ch1 = 256 + ch0;
  int r1s = ch1 >> 3, d1s = (ch1 & 7) ^ (r1s & 7);
  size_t koff0 = (size_t)r0s * QKVSTR + d0s * 8;
  size_t koff1 = (size_t)r1s * QKVSTR + d1s * 8;
  size_t voff0 = (size_t)r0s * SEQ + d0s * 8;
  size_t voff1 = (size_t)r1s * SEQ + d1s * 8;
  unsigned short* sKlo[2] = { &Ks[grp][0][(qw * 64) * 8],       &Ks[grp][1][(qw * 64) * 8] };
  unsigned short* sKhi[2] = { &Ks[grp][0][(256 + qw * 64) * 8], &Ks[grp][1][(256 + qw * 64) * 8] };
  unsigned short* sVlo[2] = { &Vs[grp][0][(qw * 64) * 8],       &Vs[grp][1][(qw * 64) * 8] };
  unsigned short* sVhi[2] = { &Vs[grp][0][(256 + qw * 64) * 8], &Vs[grp][1][(256 + qw * 64) * 8] };

  // stage Q [128][64]: 1024 chunks by 8 waves, XOR-swizzled via global source
  for (int c = 0; c < 2; ++c) {
    int chunk = c * 512 + w * 64 + lane;
    int row = chunk >> 3, pos = chunk & 7;
    int db = pos ^ (row & 7);
    gload_lds16(Qg + (size_t)(q0 + row) * QKVSTR + db * 8, Qs + (c * 512 + w * 64) * 8);
  }
  // stage this group's K/V tile 0
  {
    const unsigned short* Kt = Kg + (size_t)kvbase * QKVSTR;
    const unsigned short* Vtt = Vg + kvbase;
    gload_lds16(Kt + koff0, sKlo[0]);
    gload_lds16(Kt + koff1, sKhi[0]);
    gload_lds16(Vtt + voff0, sVlo[0]);
    gload_lds16(Vtt + voff1, sVhi[0]);
  }
  asm volatile("s_waitcnt vmcnt(4)" ::: "memory");  // Q landed; tile0 in flight
  __builtin_amdgcn_sched_barrier(0);
  __builtin_amdgcn_s_barrier();

  // Q fragments (B-operand: col q = l31, k = d); both groups read same q-rows
  bf16x8 qf[4];
  {
    int qrow = qw * 32 + l31;
    for (int dc = 0; dc < 4; ++dc) {
      int pos = 2 * dc + hi;
      qf[dc] = *(const bf16x8*)&Qs[qrow * 64 + (pos ^ (qrow & 7)) * 8];
    }
  }

  // hoisted LDS byte offsets for kf/vf (f=1 row+32 keeps &7 -> +4096B imm)
  int offb[4];
#pragma unroll
  for (int dc = 0; dc < 4; ++dc)
    offb[dc] = l31 * 128 + (((2 * dc + hi) ^ (l31 & 7)) * 16);
  const char* KbA = (const char*)&Ks[grp][0][0];
  const char* KbB = (const char*)&Ks[grp][1][0];
  const char* VbA = (const char*)&Vs[grp][0][0];
  const char* VbB = (const char*)&Vs[grp][1][0];

  f32x16 o0 = {}, o1 = {};
  float la0 = 0.f, la1 = 0.f, la2 = 0.f, la3 = 0.f;

  auto body = [&](int t, int CUR) {
    int NB = CUR ^ 1;
    int kvn = kvbase + (((t + 1) & 31) << 6);
    const unsigned short* Kt = Kg + (size_t)kvn * QKVSTR;
    const unsigned short* Vtt = Vg + kvn;
    gload_lds16(Kt + koff0, sKlo[NB]);
    gload_lds16(Kt + koff1, sKhi[NB]);
    gload_lds16(Vtt + voff0, sVlo[NB]);
    gload_lds16(Vtt + voff1, sVhi[NB]);
    asm volatile("s_waitcnt vmcnt(4)" ::: "memory");  // tile t resident (this wave)
    __builtin_amdgcn_sched_barrier(0);
    __builtin_amdgcn_s_barrier();                     // tile t resident (all waves)
    __builtin_amdgcn_sched_barrier(0);

    const char* Kb = CUR ? KbB : KbA;
    const char* Vb = CUR ? VbB : VbA;
    bf16x8 kf0[4], kf1[4];
#pragma unroll
    for (int dc = 0; dc < 4; ++dc) {
      kf0[dc] = *(const bf16x8*)(Kb + offb[dc]);
      kf1[dc] = *(const bf16x8*)(Kb + offb[dc] + 4096);
    }
    f32x16 st0 = {}, st1 = {};
    __builtin_amdgcn_s_setprio(1);
#pragma unroll
    for (int dc = 0; dc < 4; ++dc) {
      st0 = __builtin_amdgcn_mfma_f32_32x32x16_bf16(kf0[dc], qf[dc], st0, 0, 0, 0);
      st1 = __builtin_amdgcn_mfma_f32_32x32x16_bf16(kf1[dc], qf[dc], st1, 0, 0, 0);
    }
    __builtin_amdgcn_s_setprio(0);

    bf16x8 vf0[4], vf1[4];
#pragma unroll
    for (int c = 0; c < 4; ++c) {
      vf0[c] = *(const bf16x8*)(Vb + offb[c]);
      vf1[c] = *(const bf16x8*)(Vb + offb[c] + 4096);
    }

    float p0[16], p1[16];
#pragma unroll
    for (int r = 0; r < 16; r += 4) {
      p0[r] = fast_exp2(st0[r]); p0[r + 1] = fast_exp2(st0[r + 1]);
      p0[r + 2] = fast_exp2(st0[r + 2]); p0[r + 3] = fast_exp2(st0[r + 3]);
      la0 += p0[r]; la1 += p0[r + 1]; la2 += p0[r + 2]; la3 += p0[r + 3];
    }
#pragma unroll
    for (int r = 0; r < 16; r += 4) {
      p1[r] = fast_exp2(st1[r]); p1[r + 1] = fast_exp2(st1[r + 1]);
      p1[r + 2] = fast_exp2(st1[r + 2]); p1[r + 3] = fast_exp2(st1[r + 3]);
      la0 += p1[r]; la1 += p1[r + 1]; la2 += p1[r + 2]; la3 += p1[r + 3];
    }

    bf16x8 pa[4];
#pragma unroll
    for (int f = 0; f < 2; ++f) {
      const float* pp = f ? p1 : p0;
#pragma unroll
      for (int cc = 0; cc < 2; ++cc) {
        unsigned uLO0 = cvt_pk_bf16(pp[8 * cc + 0], pp[8 * cc + 1]);
        unsigned uLO1 = cvt_pk_bf16(pp[8 * cc + 2], pp[8 * cc + 3]);
        unsigned uHI0 = cvt_pk_bf16(pp[8 * cc + 4], pp[8 * cc + 5]);
        unsigned uHI1 = cvt_pk_bf16(pp[8 * cc + 6], pp[8 * cc + 7]);
        auto s0 = __builtin_amdgcn_permlane32_swap(uLO0, uHI0, false, false);
        auto s1 = __builtin_amdgcn_permlane32_swap(uLO1, uHI1, false, false);
        union { unsigned u[4]; bf16x8 v; } pw;
        pw.u[0] = s0[0]; pw.u[1] = s1[0]; pw.u[2] = s0[1]; pw.u[3] = s1[1];
        pa[f * 2 + cc] = pw.v;
      }
    }

    __builtin_amdgcn_s_setprio(1);
#pragma unroll
    for (int c = 0; c < 4; ++c) {
      o0 = __builtin_amdgcn_mfma_f32_32x32x16_bf16(pa[c], vf0[c], o0, 0, 0, 0);
      o1 = __builtin_amdgcn_mfma_f32_32x32x16_bf16(pa[c], vf1[c], o1, 0, 0, 0);
    }
    __builtin_amdgcn_s_setprio(0);

    asm volatile("" ::: "memory");
    __builtin_amdgcn_sched_barrier(0);
    __builtin_amdgcn_s_barrier();   // reads of tile t done -> next stage may overwrite
  };

  for (int tt = 0; tt < 32; tt += 2) {
    body(tt + 0, 0);
    body(tt + 1, 1);
  }

  // per-half lsum finalize (cross-hi reduce)
  float lsum = (la0 + la1) + (la2 + la3);
  lsum += __shfl_xor(lsum, 32);

  // combine halves via LDS (exact: no-max softmax partials are additive)
  __syncthreads();  // drains wrap-prefetch vmcnt; all tile reads done
  float* cbO0 = (float*)&Ks[0][0][0];  // 32 KB
  float* cbO1 = (float*)&Vs[0][0][0];  // 32 KB
  float* cbL  = (float*)&Qs[0];        // 1 KB of 16
  int cbase = (qw * 64 + lane) * 32;
  int lx = lane & 31;
  if (grp == 1) {
#pragma unroll
    for (int r = 0; r < 16; ++r) {
      cbO0[cbase + (r ^ lx)] = o0[r];
      cbO1[cbase + (r ^ lx)] = o1[r];
    }
    cbL[qw * 64 + lane] = lsum;
  }
  __syncthreads();
  if (grp == 0) {
#pragma unroll
    for (int r = 0; r < 16; ++r) {
      o0[r] += cbO0[cbase + (r ^ lx)];
      o1[r] += cbO1[cbase + (r ^ lx)];
    }
    lsum += cbL[qw * 64 + lane];
    float inv = 1.f / lsum;
#pragma unroll
    for (int r = 0; r < 16; ++r) {
      int qr = (r & 3) + 8 * (r >> 2) + 4 * hi;
      float ir = __shfl(inv, qr + (lane & 32));
      size_t row = q0 + qw * 32 + qr;
      Aout[row * DIM + h * HD + l31]      = f2bf(o0[r] * ir);
      Aout[row * DIM + h * HD + 32 + l31] = f2bf(o1[r] * ir);
    }
  }
}

extern "C" void kernel_launch(void* const* d_in, const int* in_sizes, int n_in,
                              void* d_out, int out_size, void* d_ws, size_t ws_size,
                              hipStream_t stream) {
  (void)in_sizes; (void)n_in; (void)out_size; (void)ws_size;
  const float* X  = (const float*)d_in[0];
  const float* wq = (const float*)d_in[1];
  const float* bq = (const float*)d_in[2];
  const float* wk = (const float*)d_in[3];
  const float* wv = (const float*)d_in[4];
  const float* bv = (const float*)d_in[5];
  const float* wo = (const float*)d_in[6];
  const float* bo = (const float*)d_in[7];

  char* ws = (char*)d_ws;
  const size_t SZ_XD  = (size_t)SEQ * DIM * 2;      // 8 MB
  const size_t SZ_W   = (size_t)DIM * DIM * 2;      // 2 MB
  const size_t SZ_QKV = (size_t)SEQ * QKVSTR * 2;   // 24 MB
  unsigned short* Xb   = (unsigned short*)(ws);                    // reused as Ab
  unsigned short* Wqkv = (unsigned short*)(ws + SZ_XD);            // [3072][1024]
  unsigned short* Wob  = (unsigned short*)(ws + SZ_XD + 3 * SZ_W);
  unsigned short* QKVb = (unsigned short*)(ws + SZ_XD + 4 * SZ_W); // [4096][3072]
  unsigned short* Vtb  = (unsigned short*)(ws + SZ_XD + 4 * SZ_W + SZ_QKV);
  unsigned short* Ab   = Xb;

  const float QSCALE = 0.125f * 1.44269504088896f;  // fold 1/sqrt(hd) * log2(e) into Wq/bq

  // one fused cast launch: 1048576 groups of 8 -> 4096 blocks
  cast_all_kernel<<<4096, 256, 0, stream>>>(X, wq, wk, wv, wo, Xb, Wqkv, Wob, QSCALE);

  // fused QKV projection: [4096][3072] bf16; V section written transposed to Vtb
  gemm_bt_kernel<1, 0, 128><<<dim3(QKVSTR / 128, SEQ / 128), 256, 0, stream>>>(
      Xb, Wqkv, bq, bv, QSCALE, QKVb, Vtb, SEQ, QKVSTR, DIM);

  attn_kernel<<<SEQ / 128 * NH, 512, 0, stream>>>(QKVb, Vtb, Ab);

  // output projection (f32 out): 128x64 tiles -> 512 blocks = 2/CU
  gemm_bt_kernel<2, 1, 64><<<dim3(DIM / 64, SEQ / 128), 256, 0, stream>>>(
      Ab, Wob, bo, nullptr, 1.f, d_out, nullptr, SEQ, DIM, DIM);
}

// Round 16
// 152.615 us; speedup vs baseline: 1.1266x; 1.0467x over previous
//
#include <hip/hip_runtime.h>

#define SEQ 4096
#define DIM 1024
#define NH 16
#define HD 64
#define QKVSTR 3072

typedef __attribute__((ext_vector_type(8))) short bf16x8;
typedef __attribute__((ext_vector_type(4))) float f32x4;
typedef __attribute__((ext_vector_type(16))) float f32x16;
typedef __attribute__((ext_vector_type(4))) unsigned int uint4v;

__device__ __forceinline__ unsigned short f2bf(float f) {
  unsigned int b = __float_as_uint(f);
  b = b + 0x7fffu + ((b >> 16) & 1u);
  return (unsigned short)(b >> 16);
}

__device__ __forceinline__ unsigned int cvt_pk_bf16(float lo, float hi) {
  unsigned int r;
  asm("v_cvt_pk_bf16_f32 %0, %1, %2" : "=v"(r) : "v"(lo), "v"(hi));
  return r;
}

__device__ __forceinline__ float fast_exp2(float x) {
#if __has_builtin(__builtin_amdgcn_exp2f)
  return __builtin_amdgcn_exp2f(x);
#else
  float r; asm("v_exp_f32 %0, %1" : "=v"(r) : "v"(x)); return r;
#endif
}

typedef __attribute__((address_space(3))) unsigned int lds_uint;
typedef __attribute__((address_space(1))) const unsigned int global_uint;

__device__ __forceinline__ void gload_lds16(const void* g, void* l) {
  __builtin_amdgcn_global_load_lds((global_uint*)g, (lds_uint*)l, 16, 0, 0);
}

// ---------------- fused cast fp32 -> bf16 for all 5 tensors (1 launch) ----------------
__global__ __launch_bounds__(256) void cast_all_kernel(
    const float* __restrict__ X, const float* __restrict__ wq, const float* __restrict__ wk,
    const float* __restrict__ wv, const float* __restrict__ wo,
    unsigned short* __restrict__ Xb, unsigned short* __restrict__ Wqkv,
    unsigned short* __restrict__ Wob, float qscale) {
  int i = blockIdx.x * 256 + threadIdx.x;
  const float* src;
  unsigned short* dst;
  float sc = 1.f;
  if (i < 524288) { src = X + (size_t)i * 8; dst = Xb + (size_t)i * 8; }
  else if (i < 655360) { int j = i - 524288; src = wq + (size_t)j * 8; dst = Wqkv + (size_t)j * 8; sc = qscale; }
  else if (i < 786432) { int j = i - 655360; src = wk + (size_t)j * 8; dst = Wqkv + 1048576 + (size_t)j * 8; }
  else if (i < 917504) { int j = i - 786432; src = wv + (size_t)j * 8; dst = Wqkv + 2097152 + (size_t)j * 8; }
  else { int j = i - 917504; src = wo + (size_t)j * 8; dst = Wob + (size_t)j * 8; }
  const float4* p = (const float4*)src;
  float4 x0 = p[0], x1 = p[1];
  union { unsigned short u[8]; uint4v v; } o;
  o.u[0] = f2bf(x0.x * sc); o.u[1] = f2bf(x0.y * sc);
  o.u[2] = f2bf(x0.z * sc); o.u[3] = f2bf(x0.w * sc);
  o.u[4] = f2bf(x1.x * sc); o.u[5] = f2bf(x1.y * sc);
  o.u[6] = f2bf(x1.z * sc); o.u[7] = f2bf(x1.w * sc);
  *(uint4v*)dst = o.v;
}

// ---------------- GEMM: C[M,N] = A[M,K](bf16) @ B[N,K]^T(bf16) (+bias) ----------------
// 2-DEEP prefetch, 3 LDS buffers (R15-proven). Bijective XCD swizzle.
// BIASMODE==1 additionally writes the V section (col>=2048) TRANSPOSED into Vt.
template<int BIASMODE, int OUT_F32, int BN>
__global__ __launch_bounds__(256) void gemm_bt_kernel(
    const unsigned short* __restrict__ A, const unsigned short* __restrict__ B,
    const float* __restrict__ b0, const float* __restrict__ b1, float qscale,
    void* __restrict__ Cout, unsigned short* __restrict__ Vt, int M, int N, int K) {
  constexpr int NF = BN / 32;          // n-frags per wave
  __shared__ unsigned short As[3][128 * 32];
  __shared__ unsigned short Bs[3][BN * 32];
  int tid = threadIdx.x;
  int wave = tid >> 6, lane = tid & 63;
  int g = lane >> 4, lc = lane & 15;
  int wm = wave >> 1, wn = wave & 1;

  int gx = gridDim.x;
  int wgid = blockIdx.y * gx + blockIdx.x;
  int cpx = (gx * gridDim.y) >> 3;
  int sw = (wgid & 7) * cpx + (wgid >> 3);
  int m0 = (sw / gx) * 128, n0 = (sw % gx) * BN;

  int ch0 = wave * 64 + lane;
  int r0 = ch0 >> 2, cb0 = ch0 & 3;
  int ch1 = 256 + ch0;
  int r1 = ch1 >> 2, cb1 = ch1 & 3;
  const unsigned short* Ar0 = A + (size_t)(m0 + r0) * K + cb0 * 8;
  const unsigned short* Ar1 = A + (size_t)(m0 + r1) * K + cb1 * 8;
  const unsigned short* Br0 = B + (size_t)(n0 + r0) * K + cb0 * 8;
  const unsigned short* Br1 = B + (size_t)(n0 + r1) * K + cb1 * 8;  // unused if BN==64

  unsigned short* sAlo[3] = { &As[0][(wave * 64) * 8], &As[1][(wave * 64) * 8], &As[2][(wave * 64) * 8] };
  unsigned short* sAhi[3] = { &As[0][(256 + wave * 64) * 8], &As[1][(256 + wave * 64) * 8], &As[2][(256 + wave * 64) * 8] };
  unsigned short* sBlo[3] = { &Bs[0][(wave * 64) * 8], &Bs[1][(wave * 64) * 8], &Bs[2][(wave * 64) * 8] };
  unsigned short* sBhi[3] = { &Bs[0][(256 + wave * 64) * 8], &Bs[1][(256 + wave * 64) * 8], &Bs[2][(256 + wave * 64) * 8] };

  f32x4 acc[4][NF] = {};

  auto stage = [&](int kn, int b) {
    gload_lds16(Ar0 + kn, sAlo[b]);
    gload_lds16(Ar1 + kn, sAhi[b]);
    gload_lds16(Br0 + kn, sBlo[b]);
    if (BN == 128) gload_lds16(Br1 + kn, sBhi[b]);
  };

  auto compute = [&](int b) {
    bf16x8 af[4], bfr[NF];
    for (int mf = 0; mf < 4; ++mf)
      af[mf] = *(const bf16x8*)&As[b][(wm * 64 + mf * 16 + lc) * 32 + g * 8];
    for (int nf = 0; nf < NF; ++nf)
      bfr[nf] = *(const bf16x8*)&Bs[b][(wn * (BN / 2) + nf * 16 + lc) * 32 + g * 8];
    for (int mf = 0; mf < 4; ++mf)
      for (int nf = 0; nf < NF; ++nf)
        acc[mf][nf] = __builtin_amdgcn_mfma_f32_16x16x32_bf16(af[mf], bfr[nf], acc[mf][nf], 0, 0, 0);
  };

  const int NT = K / 32;  // 32 K-steps
  auto step = [&](int i, int CUR, int STG) {
    int kn = (i + 2 < NT) ? (i + 2) * 32 : 0;  // wrap: dummy reload of k=0
    stage(kn, STG);
    if (BN == 128) {
      asm volatile("s_waitcnt vmcnt(8)" ::: "memory");   // tile i resident; i+1,i+2 in flight
    } else {
      asm volatile("s_waitcnt vmcnt(6)" ::: "memory");
    }
    __builtin_amdgcn_sched_barrier(0);
    __builtin_amdgcn_s_barrier();
    __builtin_amdgcn_sched_barrier(0);
    compute(CUR);
    asm volatile("" ::: "memory");
    __builtin_amdgcn_sched_barrier(0);
    __builtin_amdgcn_s_barrier();   // reads of tile i done -> buf may be overwritten next iter
  };

  stage(0, 0);
  stage(32, 1);

  for (int ii = 0; ii < 30; ii += 3) {
    step(ii + 0, 0, 2);
    step(ii + 1, 1, 0);
    step(ii + 2, 2, 1);
  }
  step(30, 0, 2);
  step(31, 1, 0);

  for (int nf = 0; nf < NF; ++nf) {
    int col = n0 + wn * (BN / 2) + nf * 16 + lc;
    float bias = 0.f;
    if (BIASMODE == 1) {
      int sect = col >> 10, cc = col & 1023;
      bias = (sect == 0) ? b0[cc] * qscale : ((sect == 2) ? b1[cc] : 0.f);
    } else if (BIASMODE == 2) {
      bias = b0[col];
    }
    for (int mf = 0; mf < 4; ++mf) {
      int row = m0 + wm * 64 + mf * 16 + g * 4;
      for (int r = 0; r < 4; ++r) {
        float v = acc[mf][nf][r] + bias;
        if (OUT_F32) {
          ((float*)Cout)[(size_t)(row + r) * N + col] = v;
        } else if (BIASMODE == 1 && col >= 2048) {
          Vt[(size_t)(col - 2048) * SEQ + row + r] = f2bf(v);
        } else {
          ((unsigned short*)Cout)[(size_t)(row + r) * N + col] = f2bf(v);
        }
      }
    }
  }
}

// ---------------- flash attention: 8-wave kv-split, KVBLK=32, 48KB LDS (3 blocks/CU) ----------------
// R13 body with half-size K/V tiles: per group 64 tiles of 32 kv. Same sync
// skeleton (2 bufs, 2 barriers/tile, counted vmcnt(2), never 0). SMEM manually
// partitioned: Q [0,16K), K [16K,32K), V [32K,48K). Combine is two-pass
// (o0 then o1) through a 32KB region. V-tile rows are 64B -> XOR-4 swizzle.
__global__ __launch_bounds__(512, 1) void attn_kernel(
    const unsigned short* __restrict__ QKV, const unsigned short* __restrict__ Vt,
    unsigned short* __restrict__ Aout) {
  __shared__ unsigned short SMEM[24576];  // 48 KB
  unsigned short* Qs = SMEM;                                   // 8192 elems
  int tid = threadIdx.x;
  int w = tid >> 6, lane = tid & 63;
  int hi = lane >> 5, l31 = lane & 31;
  int qw = w & 3, grp = w >> 2;

  // XCD swizzle: 512 blocks, 8 XCDs -> XCD x owns heads 2x..2x+1 (K/V fit 4MB L2)
  int bid = blockIdx.x;
  int swz = (bid & 7) * 64 + (bid >> 3);
  int h = swz >> 5;
  int q0 = (swz & 31) * 128;

  const unsigned short* Qg = QKV + h * HD;
  const unsigned short* Kg = QKV + DIM + h * HD;
  const unsigned short* Vg = Vt + (size_t)(h * HD) * SEQ;
  int kvbase = grp * (SEQ / 2);

  // per-group LDS tile bases (elems): K tile 2048 (32x64), V tile 2048 (64x32)
  unsigned short* Kt0 = SMEM + 8192 + (grp * 2 + 0) * 2048;
  unsigned short* Kt1 = SMEM + 8192 + (grp * 2 + 1) * 2048;
  unsigned short* Vt0 = SMEM + 16384 + (grp * 2 + 0) * 2048;
  unsigned short* Vt1 = SMEM + 16384 + (grp * 2 + 1) * 2048;

  // staging: 256 chunks per tile, 1 chunk/lane (ch = qw*64+lane)
  int ch = qw * 64 + lane;
  int krow = ch >> 3, kpos = (ch & 7) ^ (krow & 7);            // K: rows of 8 chunks (128B)
  int vrow = ch >> 2, vpos = (ch & 3) ^ (vrow & 3);            // V: rows of 4 chunks (64B)
  size_t koff = (size_t)krow * QKVSTR + kpos * 8;
  size_t voff = (size_t)vrow * SEQ + vpos * 8;
  unsigned short* sK[2] = { Kt0 + ch * 8 - lane * 8 + lane * 8, Kt1 + ch * 8 - lane * 8 + lane * 8 };
  // (dest must be wave-uniform base + lane*16B: base = tile + qw*64*8, lane offset implicit)
  unsigned short* sKb[2] = { Kt0 + (qw * 64) * 8, Kt1 + (qw * 64) * 8 };
  unsigned short* sVb[2] = { Vt0 + (qw * 64) * 8, Vt1 + (qw * 64) * 8 };

  // stage Q [128][64]: 1024 chunks by 8 waves, XOR-8 swizzled via global source
  for (int c = 0; c < 2; ++c) {
    int chunk = c * 512 + w * 64 + lane;
    int row = chunk >> 3, pos = chunk & 7;
    int db = pos ^ (row & 7);
    gload_lds16(Qg + (size_t)(q0 + row) * QKVSTR + db * 8, Qs + (c * 512 + w * 64) * 8);
  }
  // stage this group's K/V tile 0 (2 loads)
  gload_lds16(Kg + (size_t)kvbase * QKVSTR + koff, sKb[0]);
  gload_lds16(Vg + kvbase + voff, sVb[0]);
  asm volatile("s_waitcnt vmcnt(2)" ::: "memory");  // Q landed; tile0 in flight
  __builtin_amdgcn_sched_barrier(0);
  __builtin_amdgcn_s_barrier();

  // Q fragments (B-operand: col q = l31, k = d); both groups read same q-rows
  bf16x8 qf[4];
  {
    int qrow = qw * 32 + l31;
    for (int dc = 0; dc < 4; ++dc) {
      int pos = 2 * dc + hi;
      qf[dc] = *(const bf16x8*)&Qs[qrow * 64 + (pos ^ (qrow & 7)) * 8];
    }
  }

  // hoisted LDS byte offsets
  int kOffb[4], vOffb[2];
#pragma unroll
  for (int dc = 0; dc < 4; ++dc)
    kOffb[dc] = l31 * 128 + (((2 * dc + hi) ^ (l31 & 7)) * 16);
#pragma unroll
  for (int c = 0; c < 2; ++c)
    vOffb[c] = l31 * 64 + (((2 * c + hi) ^ (l31 & 3)) * 16);
  const char* KbA = (const char*)Kt0;
  const char* KbB = (const char*)Kt1;
  const char* VbA = (const char*)Vt0;
  const char* VbB = (const char*)Vt1;

  f32x16 o0 = {}, o1 = {};
  float la0 = 0.f, la1 = 0.f, la2 = 0.f, la3 = 0.f;

  auto body = [&](int t, int CUR) {
    int NB = CUR ^ 1;
    int kvn = kvbase + (((t + 1) & 63) << 5);
    gload_lds16(Kg + (size_t)kvn * QKVSTR + koff, sKb[NB]);
    gload_lds16(Vg + kvn + voff, sVb[NB]);
    asm volatile("s_waitcnt vmcnt(2)" ::: "memory");  // tile t resident (this wave)
    __builtin_amdgcn_sched_barrier(0);
    __builtin_amdgcn_s_barrier();                     // tile t resident (all waves)
    __builtin_amdgcn_sched_barrier(0);

    const char* Kb = CUR ? KbB : KbA;
    const char* Vb = CUR ? VbB : VbA;
    bf16x8 kf[4];
#pragma unroll
    for (int dc = 0; dc < 4; ++dc)
      kf[dc] = *(const bf16x8*)(Kb + kOffb[dc]);
    f32x16 st0 = {};
    __builtin_amdgcn_s_setprio(1);
#pragma unroll
    for (int dc = 0; dc < 4; ++dc)
      st0 = __builtin_amdgcn_mfma_f32_32x32x16_bf16(kf[dc], qf[dc], st0, 0, 0, 0);
    __builtin_amdgcn_s_setprio(0);

    // V fragments early (latency hides under exp/pack)
    bf16x8 vf0[2], vf1[2];
#pragma unroll
    for (int c = 0; c < 2; ++c) {
      vf0[c] = *(const bf16x8*)(Vb + vOffb[c]);
      vf1[c] = *(const bf16x8*)(Vb + vOffb[c] + 2048);
    }

    // P = exp2(S^T); 4 independent lsum accumulators
    float p0[16];
#pragma unroll
    for (int r = 0; r < 16; r += 4) {
      p0[r] = fast_exp2(st0[r]); p0[r + 1] = fast_exp2(st0[r + 1]);
      p0[r + 2] = fast_exp2(st0[r + 2]); p0[r + 3] = fast_exp2(st0[r + 3]);
      la0 += p0[r]; la1 += p0[r + 1]; la2 += p0[r + 2]; la3 += p0[r + 3];
    }

    // pack to bf16 + permlane32_swap -> PV A-frags pa[0..1] (T12)
    bf16x8 pa[2];
#pragma unroll
    for (int cc = 0; cc < 2; ++cc) {
      unsigned uLO0 = cvt_pk_bf16(p0[8 * cc + 0], p0[8 * cc + 1]);
      unsigned uLO1 = cvt_pk_bf16(p0[8 * cc + 2], p0[8 * cc + 3]);
      unsigned uHI0 = cvt_pk_bf16(p0[8 * cc + 4], p0[8 * cc + 5]);
      unsigned uHI1 = cvt_pk_bf16(p0[8 * cc + 6], p0[8 * cc + 7]);
      auto s0 = __builtin_amdgcn_permlane32_swap(uLO0, uHI0, false, false);
      auto s1 = __builtin_amdgcn_permlane32_swap(uLO1, uHI1, false, false);
      union { unsigned u[4]; bf16x8 v; } pw;
      pw.u[0] = s0[0]; pw.u[1] = s1[0]; pw.u[2] = s0[1]; pw.u[3] = s1[1];
      pa[cc] = pw.v;
    }

    // PV
    __builtin_amdgcn_s_setprio(1);
#pragma unroll
    for (int c = 0; c < 2; ++c) {
      o0 = __builtin_amdgcn_mfma_f32_32x32x16_bf16(pa[c], vf0[c], o0, 0, 0, 0);
      o1 = __builtin_amdgcn_mfma_f32_32x32x16_bf16(pa[c], vf1[c], o1, 0, 0, 0);
    }
    __builtin_amdgcn_s_setprio(0);

    asm volatile("" ::: "memory");
    __builtin_amdgcn_sched_barrier(0);
    __builtin_amdgcn_s_barrier();   // reads of tile t done -> next stage may overwrite
  };

  for (int tt = 0; tt < 64; tt += 2) {
    body(tt + 0, 0);
    body(tt + 1, 1);
  }

  // per-half lsum finalize (cross-hi reduce)
  float lsum = (la0 + la1) + (la2 + la3);
  lsum += __shfl_xor(lsum, 32);

  // combine halves (exact; two passes through 32KB region)
  float* cb = (float*)SMEM;               // 8192 floats
  float* cbL = (float*)(SMEM + 16384);    // 256 floats
  int cbase = (qw * 64 + lane) * 32;
  int lx = lane & 31;
  __syncthreads();  // drains wrap-prefetch vmcnt; all tile reads done
  if (grp == 1) {
#pragma unroll
    for (int r = 0; r < 16; ++r) cb[cbase + (r ^ lx)] = o0[r];
    cbL[qw * 64 + lane] = lsum;
  }
  __syncthreads();
  if (grp == 0) {
#pragma unroll
    for (int r = 0; r < 16; ++r) o0[r] += cb[cbase + (r ^ lx)];
    lsum += cbL[qw * 64 + lane];
  }
  __syncthreads();
  if (grp == 1) {
#pragma unroll
    for (int r = 0; r < 16; ++r) cb[cbase + (r ^ lx)] = o1[r];
  }
  __syncthreads();
  if (grp == 0) {
#pragma unroll
    for (int r = 0; r < 16; ++r) o1[r] += cb[cbase + (r ^ lx)];
    float inv = 1.f / lsum;
#pragma unroll
    for (int r = 0; r < 16; ++r) {
      int qr = (r & 3) + 8 * (r >> 2) + 4 * hi;
      float ir = __shfl(inv, qr + (lane & 32));
      size_t row = q0 + qw * 32 + qr;
      Aout[row * DIM + h * HD + l31]      = f2bf(o0[r] * ir);
      Aout[row * DIM + h * HD + 32 + l31] = f2bf(o1[r] * ir);
    }
  }
}

extern "C" void kernel_launch(void* const* d_in, const int* in_sizes, int n_in,
                              void* d_out, int out_size, void* d_ws, size_t ws_size,
                              hipStream_t stream) {
  (void)in_sizes; (void)n_in; (void)out_size; (void)ws_size;
  const float* X  = (const float*)d_in[0];
  const float* wq = (const float*)d_in[1];
  const float* bq = (const float*)d_in[2];
  const float* wk = (const float*)d_in[3];
  const float* wv = (const float*)d_in[4];
  const float* bv = (const float*)d_in[5];
  const float* wo = (const float*)d_in[6];
  const float* bo = (const float*)d_in[7];

  char* ws = (char*)d_ws;
  const size_t SZ_XD  = (size_t)SEQ * DIM * 2;      // 8 MB
  const size_t SZ_W   = (size_t)DIM * DIM * 2;      // 2 MB
  const size_t SZ_QKV = (size_t)SEQ * QKVSTR * 2;   // 24 MB
  unsigned short* Xb   = (unsigned short*)(ws);                    // reused as Ab
  unsigned short* Wqkv = (unsigned short*)(ws + SZ_XD);            // [3072][1024]
  unsigned short* Wob  = (unsigned short*)(ws + SZ_XD + 3 * SZ_W);
  unsigned short* QKVb = (unsigned short*)(ws + SZ_XD + 4 * SZ_W); // [4096][3072]
  unsigned short* Vtb  = (unsigned short*)(ws + SZ_XD + 4 * SZ_W + SZ_QKV);
  unsigned short* Ab   = Xb;

  const float QSCALE = 0.125f * 1.44269504088896f;  // fold 1/sqrt(hd) * log2(e) into Wq/bq

  // one fused cast launch: 1048576 groups of 8 -> 4096 blocks
  cast_all_kernel<<<4096, 256, 0, stream>>>(X, wq, wk, wv, wo, Xb, Wqkv, Wob, QSCALE);

  // fused QKV projection: [4096][3072] bf16; V section written transposed to Vtb
  gemm_bt_kernel<1, 0, 128><<<dim3(QKVSTR / 128, SEQ / 128), 256, 0, stream>>>(
      Xb, Wqkv, bq, bv, QSCALE, QKVb, Vtb, SEQ, QKVSTR, DIM);

  attn_kernel<<<SEQ / 128 * NH, 512, 0, stream>>>(QKVb, Vtb, Ab);

  // output projection (f32 out): 128x64 tiles -> 512 blocks = 2/CU
  gemm_bt_kernel<2, 1, 64><<<dim3(DIM / 64, SEQ / 128), 256, 0, stream>>>(
      Ab, Wob, bo, nullptr, 1.f, d_out, nullptr, SEQ, DIM, DIM);
}